// Round 1
// baseline (1623.182 us; speedup 1.0000x reference)
//
#include <hip/hip_runtime.h>

#define Nn 8192
#define Mm 64
#define Bb 8
#define Kk 3
#define SOMK 9
#define KN (Kk * Nn)  // 24576

__device__ __constant__ float INV_BN_C = 0.9999950000374997f;

// ---------------- SOM assignment: top-3 nearest nodes per point ----------------
__global__ __launch_bounds__(256) void som_assign_kernel(
    const float* __restrict__ x, const float* __restrict__ node,
    int* __restrict__ min_idx, float* __restrict__ counts, float* __restrict__ cl_sum) {
  int b = blockIdx.y;
  int n = blockIdx.x * 256 + threadIdx.x;
  __shared__ float nd[3][Mm];
  __shared__ float s_cnt[Mm];
  __shared__ float s_sum[Mm][3];
  int t = threadIdx.x;
  if (t < 192) nd[t / 64][t % 64] = node[(b * 3 + t / 64) * Mm + (t % 64)];
  if (t < Mm) { s_cnt[t] = 0.f; s_sum[t][0] = 0.f; s_sum[t][1] = 0.f; s_sum[t][2] = 0.f; }
  __syncthreads();
  float x0 = x[(b * 3 + 0) * Nn + n];
  float x1 = x[(b * 3 + 1) * Nn + n];
  float x2 = x[(b * 3 + 2) * Nn + n];
  float b0 = 1e30f, b1 = 1e30f, b2 = 1e30f;
  int j0 = 0, j1 = 0, j2 = 0;
  for (int m = 0; m < Mm; ++m) {
    float dx = x0 - nd[0][m];
    float dy = x1 - nd[1][m];
    float dz = x2 - nd[2][m];
    // no-FMA-contraction distance to match reference rounding (selection input!)
    float d = __fadd_rn(__fadd_rn(__fmul_rn(dx, dx), __fmul_rn(dy, dy)), __fmul_rn(dz, dz));
    if (d < b0)      { b2 = b1; j2 = j1; b1 = b0; j1 = j0; b0 = d; j0 = m; }
    else if (d < b1) { b2 = b1; j2 = j1; b1 = d; j1 = m; }
    else if (d < b2) { b2 = d; j2 = m; }
  }
  min_idx[b * KN + 0 * Nn + n] = j0;
  min_idx[b * KN + 1 * Nn + n] = j1;
  min_idx[b * KN + 2 * Nn + n] = j2;
  atomicAdd(&s_cnt[j0], 1.f);
  atomicAdd(&s_cnt[j1], 1.f);
  atomicAdd(&s_cnt[j2], 1.f);
  atomicAdd(&s_sum[j0][0], x0); atomicAdd(&s_sum[j0][1], x1); atomicAdd(&s_sum[j0][2], x2);
  atomicAdd(&s_sum[j1][0], x0); atomicAdd(&s_sum[j1][1], x1); atomicAdd(&s_sum[j1][2], x2);
  atomicAdd(&s_sum[j2][0], x0); atomicAdd(&s_sum[j2][1], x1); atomicAdd(&s_sum[j2][2], x2);
  __syncthreads();
  if (t < Mm) {
    atomicAdd(&counts[b * Mm + t], s_cnt[t]);
    atomicAdd(&cl_sum[(b * Mm + t) * 3 + 0], s_sum[t][0]);
    atomicAdd(&cl_sum[(b * Mm + t) * 3 + 1], s_sum[t][1]);
    atomicAdd(&cl_sum[(b * Mm + t) * 3 + 2], s_sum[t][2]);
  }
}

// ---------------- som_node = cl_sum / (counts + 1e-5) ----------------
__global__ __launch_bounds__(256) void som_node_kernel(
    const float* __restrict__ cl_sum, const float* __restrict__ counts,
    float* __restrict__ som_node) {
  int i = blockIdx.x * 256 + threadIdx.x;  // over B*3*M = 1536
  if (i >= Bb * 3 * Mm) return;
  int b = i / (3 * Mm), r = i % (3 * Mm), c = r / Mm, m = r % Mm;
  som_node[i] = cl_sum[(b * Mm + m) * 3 + c] / (counts[b * Mm + m] + 1e-5f);
}

// ---------------- build h = concat(x_dec, sn_rep)  [6][Pc] ----------------
__global__ __launch_bounds__(256) void build_h_kernel(
    const float* __restrict__ x, const float* __restrict__ sn,
    const float* __restrict__ som_node, const int* __restrict__ min_idx,
    float* __restrict__ h, int b0, int Pc) {
  int gid = blockIdx.x * 256 + threadIdx.x;
  if (gid >= 6 * Pc) return;
  int c = gid / Pc, pl = gid % Pc;
  int bl = pl / KN, i = pl % KN;
  int b = b0 + bl;
  int n = i % Nn;
  if (c < 3) {
    int idx = min_idx[b * KN + i];
    h[gid] = x[(b * 3 + c) * Nn + n] - som_node[(b * 3 + c) * Mm + idx];
  } else {
    h[gid] = sn[(b * 3 + (c - 3)) * Nn + n];
  }
}

// ---------------- generic f32 GEMM + bias/BN/ReLU epilogue ----------------
// A: [cin][P], W: [cout][cin], prm: [3][cout] (bias,gamma,beta), out: [cout][P]
// grid: (P/64, cout/64), block 256, thread tile 4x4
__global__ __launch_bounds__(256) void conv_gemm_kernel(
    const float* __restrict__ A, const float* __restrict__ W,
    const float* __restrict__ prm, float* __restrict__ out,
    int cin, int cout, int P) {
  __shared__ float Ws[16][68];
  __shared__ float As[16][64];
  int tid = threadIdx.x;
  int tx = tid % 16, ty = tid / 16;
  int p0 = blockIdx.x * 64, d0 = blockIdx.y * 64;
  float acc[4][4] = {};
  for (int k0 = 0; k0 < cin; k0 += 16) {
#pragma unroll
    for (int it = 0; it < 4; ++it) {
      int k = tid % 16, dl = tid / 16 + it * 16;
      float w = 0.f;
      if (k0 + k < cin) w = W[(size_t)(d0 + dl) * cin + k0 + k];
      Ws[k][dl] = w;
    }
#pragma unroll
    for (int it = 0; it < 4; ++it) {
      int pl = tid % 64, kl = tid / 64 + it * 4;
      float a = 0.f;
      if (k0 + kl < cin) a = A[(size_t)(k0 + kl) * P + p0 + pl];
      As[kl][pl] = a;
    }
    __syncthreads();
#pragma unroll
    for (int kk = 0; kk < 16; ++kk) {
      float4 av = *reinterpret_cast<const float4*>(&As[kk][tx * 4]);
      float4 wv = *reinterpret_cast<const float4*>(&Ws[kk][ty * 4]);
      float a4[4] = {av.x, av.y, av.z, av.w};
      float w4[4] = {wv.x, wv.y, wv.z, wv.w};
#pragma unroll
      for (int i2 = 0; i2 < 4; ++i2)
#pragma unroll
        for (int j = 0; j < 4; ++j) acc[i2][j] += w4[i2] * a4[j];
    }
    __syncthreads();
  }
#pragma unroll
  for (int i2 = 0; i2 < 4; ++i2) {
    int d = d0 + ty * 4 + i2;
    float bi = prm[d], ga = prm[cout + d], be = prm[2 * cout + d];
    float gs = ga * INV_BN_C;
#pragma unroll
    for (int j = 0; j < 4; ++j) {
      float v = (acc[i2][j] + bi) * gs + be;
      out[(size_t)d * P + p0 + tx * 4 + j] = v > 0.f ? v : 0.f;
    }
  }
}

// ---------------- segment max: node_feat[b][m][d] = max over assigned points ----------------
__global__ __launch_bounds__(256) void segmax_kernel(
    const float* __restrict__ first_out, const int* __restrict__ min_idx,
    float* __restrict__ node_feat, int b0, int Pc) {
  int d = blockIdx.x;   // 0..383
  int bl = blockIdx.y;  // local batch
  int b = b0 + bl;
  __shared__ unsigned s_max[Mm];
  int t = threadIdx.x;
  if (t < Mm) s_max[t] = 0u;  // relu outputs >= 0; empty cluster -> 0 (matches mask)
  __syncthreads();
  const float* src = first_out + (size_t)d * Pc + (size_t)bl * KN;
  const int* mi = min_idx + b * KN;
  for (int i = t; i < KN; i += 256) {
    float v = src[i];
    int m = mi[i];
    atomicMax(&s_max[m], __float_as_uint(v));
  }
  __syncthreads();
  if (t < Mm) node_feat[((size_t)b * Mm + t) * 384 + d] = __uint_as_float(s_max[t]);
}

// ---------------- build g = concat(co_dec, f_nb)  [387][4608]; also center ----------------
__global__ __launch_bounds__(256) void build_g_kernel(
    const float* __restrict__ som_node, const float* __restrict__ node_feat,
    const int* __restrict__ knnI, float* __restrict__ g, float* __restrict__ centerb) {
  const int P2 = Bb * Mm * SOMK;  // 4608
  int gid = blockIdx.x * 256 + threadIdx.x;
  if (gid >= 387 * P2) return;
  int c = gid / P2, p = gid % P2;
  int b = p / (Mm * SOMK), r = p % (Mm * SOMK), m = r / SOMK, s = r % SOMK;
  int idx = knnI[(b * Mm + m) * SOMK + s];
  if (c < 3) {
    float sum = 0.f;
    for (int ss = 0; ss < SOMK; ++ss) {
      int ii = knnI[(b * Mm + m) * SOMK + ss];
      sum += som_node[(b * 3 + c) * Mm + ii];
    }
    float ctr = sum / 9.f;
    g[gid] = som_node[(b * 3 + c) * Mm + idx] - ctr;
    if (s == 0) centerb[(b * 3 + c) * Mm + m] = ctr;
  } else {
    g[gid] = node_feat[((size_t)b * Mm + idx) * 384 + (c - 3)];
  }
}

// ---------------- z = concat(center, max_s knn_out)  [515][512] ----------------
__global__ __launch_bounds__(256) void build_z_kernel(
    const float* __restrict__ centerb, const float* __restrict__ g3, float* __restrict__ z) {
  const int P3 = Bb * Mm;  // 512
  int gid = blockIdx.x * 256 + threadIdx.x;
  if (gid >= 515 * P3) return;
  int c = gid / P3, p = gid % P3;
  int b = p / Mm, m = p % Mm;
  if (c < 3) {
    z[gid] = centerb[(b * 3 + c) * Mm + m];
  } else {
    int d = c - 3;
    const float* src = g3 + (size_t)d * (Bb * Mm * SOMK) + b * (Mm * SOMK) + m * SOMK;
    float v = src[0];
    for (int s = 1; s < SOMK; ++s) v = fmaxf(v, src[s]);
    z[gid] = v;
  }
}

// ---------------- out[b][d] = max over m of z2[d][b*64+m] ----------------
__global__ __launch_bounds__(256) void final_max_kernel(
    const float* __restrict__ z2, float* __restrict__ out) {
  int gid = blockIdx.x * 256 + threadIdx.x;  // 8192
  if (gid >= Bb * 1024) return;
  int b = gid / 1024, d = gid % 1024;
  const float* src = z2 + (size_t)d * (Bb * Mm) + b * Mm;
  float v = src[0];
  for (int m = 1; m < Mm; ++m) v = fmaxf(v, src[m]);
  out[gid] = v;
}

extern "C" void kernel_launch(void* const* d_in, const int* in_sizes, int n_in,
                              void* d_out, int out_size, void* d_ws, size_t ws_size,
                              hipStream_t stream) {
  (void)in_sizes; (void)n_in; (void)out_size;
  const float* x = (const float*)d_in[0];
  const float* sn = (const float*)d_in[1];
  const float* node = (const float*)d_in[2];
  const int* knnI = (const int*)d_in[3];
  const float* Wfp0 = (const float*)d_in[4];  const float* Pfp0 = (const float*)d_in[5];
  const float* Wfp1 = (const float*)d_in[6];  const float* Pfp1 = (const float*)d_in[7];
  const float* Wfp2 = (const float*)d_in[8];  const float* Pfp2 = (const float*)d_in[9];
  const float* Wfp3 = (const float*)d_in[10]; const float* Pfp3 = (const float*)d_in[11];
  const float* Wk0  = (const float*)d_in[12]; const float* Pk0  = (const float*)d_in[13];
  const float* Wk1  = (const float*)d_in[14]; const float* Pk1  = (const float*)d_in[15];
  const float* Wf0  = (const float*)d_in[16]; const float* Pf0  = (const float*)d_in[17];
  const float* Wf1  = (const float*)d_in[18]; const float* Pf1  = (const float*)d_in[19];
  float* out = (float*)d_out;

  char* ws = (char*)d_ws;
  size_t off = 0;
  auto alloc = [&](size_t bytes) -> void* {
    void* p = ws + off;
    off += (bytes + 255) & ~(size_t)255;
    return p;
  };
  float* counts    = (float*)alloc(512 * 4);
  float* cl_sum    = (float*)alloc(1536 * 4);
  float* som_node  = (float*)alloc(1536 * 4);
  float* centerb   = (float*)alloc(1536 * 4);
  int*   min_idx   = (int*)alloc((size_t)Bb * KN * 4);
  float* node_feat = (float*)alloc((size_t)Bb * Mm * 384 * 4);
  float* g   = (float*)alloc(387ull * 4608 * 4);
  float* g2  = (float*)alloc(512ull * 4608 * 4);
  float* g3  = (float*)alloc(512ull * 4608 * 4);
  float* zb  = (float*)alloc(515ull * 512 * 4);
  float* z1  = (float*)alloc(768ull * 512 * 4);
  float* z2  = (float*)alloc(1024ull * 512 * 4);
  size_t small_end = off;

  // big per-chunk buffers: (6+320+128+384) ch * Bc*KN * 4B; pick largest chunk that fits
  size_t per_b = 838ull * KN * 4;
  int Bc = 1;
  if (small_end + 8 * per_b + 4096 <= ws_size) Bc = 8;
  else if (small_end + 4 * per_b + 4096 <= ws_size) Bc = 4;
  else if (small_end + 2 * per_b + 4096 <= ws_size) Bc = 2;
  int Pc = Bc * KN;
  float* h      = (float*)alloc(6ull * Pc * 4);
  float* buf320 = (float*)alloc(320ull * Pc * 4);
  float* y1b    = (float*)alloc(128ull * Pc * 4);
  float* fo     = (float*)alloc(384ull * Pc * 4);

  hipMemsetAsync(counts, 0, 512 * 4, stream);
  hipMemsetAsync(cl_sum, 0, 1536 * 4, stream);
  som_assign_kernel<<<dim3(Nn / 256, Bb), 256, 0, stream>>>(x, node, min_idx, counts, cl_sum);
  som_node_kernel<<<6, 256, 0, stream>>>(cl_sum, counts, som_node);

  for (int b0 = 0; b0 < Bb; b0 += Bc) {
    build_h_kernel<<<(6 * Pc) / 256, 256, 0, stream>>>(x, sn, som_node, min_idx, h, b0, Pc);
    conv_gemm_kernel<<<dim3(Pc / 64, 1), 256, 0, stream>>>(h, Wfp0, Pfp0, buf320, 6, 64, Pc);
    conv_gemm_kernel<<<dim3(Pc / 64, 2), 256, 0, stream>>>(buf320, Wfp1, Pfp1, y1b, 64, 128, Pc);
    conv_gemm_kernel<<<dim3(Pc / 64, 4), 256, 0, stream>>>(y1b, Wfp2, Pfp2, buf320 + 64ull * Pc, 128, 256, Pc);
    conv_gemm_kernel<<<dim3(Pc / 64, 6), 256, 0, stream>>>(buf320, Wfp3, Pfp3, fo, 320, 384, Pc);
    segmax_kernel<<<dim3(384, Bc), 256, 0, stream>>>(fo, min_idx, node_feat, b0, Pc);
  }

  build_g_kernel<<<(387 * 4608) / 256, 256, 0, stream>>>(som_node, node_feat, knnI, g, centerb);
  conv_gemm_kernel<<<dim3(4608 / 64, 8), 256, 0, stream>>>(g, Wk0, Pk0, g2, 387, 512, 4608);
  conv_gemm_kernel<<<dim3(4608 / 64, 8), 256, 0, stream>>>(g2, Wk1, Pk1, g3, 512, 512, 4608);
  build_z_kernel<<<(515 * 512 + 255) / 256, 256, 0, stream>>>(centerb, g3, zb);
  conv_gemm_kernel<<<dim3(8, 12), 256, 0, stream>>>(zb, Wf0, Pf0, z1, 515, 768, 512);
  conv_gemm_kernel<<<dim3(8, 16), 256, 0, stream>>>(z1, Wf1, Pf1, z2, 768, 1024, 512);
  final_max_kernel<<<32, 256, 0, stream>>>(z2, out);
}

// Round 2
// 1066.967 us; speedup vs baseline: 1.5213x; 1.5213x over previous
//
#include <hip/hip_runtime.h>

#define Nn 8192
#define Mm 64
#define Bb 8
#define Kk 3
#define SOMK 9
#define KN (Kk * Nn)  // 24576

__device__ __constant__ float INV_BN_C = 0.9999950000374997f;

typedef short bf16x8 __attribute__((ext_vector_type(8)));
typedef float f32x4 __attribute__((ext_vector_type(4)));

__device__ __forceinline__ unsigned short f2bf(float f) {
  unsigned int u = __float_as_uint(f);
  return (unsigned short)((u + 0x7fffu + ((u >> 16) & 1u)) >> 16);
}
__device__ __forceinline__ float bf2f(unsigned short h) {
  return __uint_as_float(((unsigned int)h) << 16);
}

// ---------------- SOM assignment: top-3 nearest nodes per point ----------------
__global__ __launch_bounds__(256) void som_assign_kernel(
    const float* __restrict__ x, const float* __restrict__ node,
    int* __restrict__ min_idx, float* __restrict__ counts, float* __restrict__ cl_sum) {
  int b = blockIdx.y;
  int n = blockIdx.x * 256 + threadIdx.x;
  __shared__ float nd[3][Mm];
  __shared__ float s_cnt[Mm];
  __shared__ float s_sum[Mm][3];
  int t = threadIdx.x;
  if (t < 192) nd[t / 64][t % 64] = node[(b * 3 + t / 64) * Mm + (t % 64)];
  if (t < Mm) { s_cnt[t] = 0.f; s_sum[t][0] = 0.f; s_sum[t][1] = 0.f; s_sum[t][2] = 0.f; }
  __syncthreads();
  float x0 = x[(b * 3 + 0) * Nn + n];
  float x1 = x[(b * 3 + 1) * Nn + n];
  float x2 = x[(b * 3 + 2) * Nn + n];
  float b0 = 1e30f, b1 = 1e30f, b2 = 1e30f;
  int j0 = 0, j1 = 0, j2 = 0;
  for (int m = 0; m < Mm; ++m) {
    float dx = x0 - nd[0][m];
    float dy = x1 - nd[1][m];
    float dz = x2 - nd[2][m];
    float d = __fadd_rn(__fadd_rn(__fmul_rn(dx, dx), __fmul_rn(dy, dy)), __fmul_rn(dz, dz));
    if (d < b0)      { b2 = b1; j2 = j1; b1 = b0; j1 = j0; b0 = d; j0 = m; }
    else if (d < b1) { b2 = b1; j2 = j1; b1 = d; j1 = m; }
    else if (d < b2) { b2 = d; j2 = m; }
  }
  min_idx[b * KN + 0 * Nn + n] = j0;
  min_idx[b * KN + 1 * Nn + n] = j1;
  min_idx[b * KN + 2 * Nn + n] = j2;
  atomicAdd(&s_cnt[j0], 1.f);
  atomicAdd(&s_cnt[j1], 1.f);
  atomicAdd(&s_cnt[j2], 1.f);
  atomicAdd(&s_sum[j0][0], x0); atomicAdd(&s_sum[j0][1], x1); atomicAdd(&s_sum[j0][2], x2);
  atomicAdd(&s_sum[j1][0], x0); atomicAdd(&s_sum[j1][1], x1); atomicAdd(&s_sum[j1][2], x2);
  atomicAdd(&s_sum[j2][0], x0); atomicAdd(&s_sum[j2][1], x1); atomicAdd(&s_sum[j2][2], x2);
  __syncthreads();
  if (t < Mm) {
    atomicAdd(&counts[b * Mm + t], s_cnt[t]);
    atomicAdd(&cl_sum[(b * Mm + t) * 3 + 0], s_sum[t][0]);
    atomicAdd(&cl_sum[(b * Mm + t) * 3 + 1], s_sum[t][1]);
    atomicAdd(&cl_sum[(b * Mm + t) * 3 + 2], s_sum[t][2]);
  }
}

__global__ __launch_bounds__(256) void som_node_kernel(
    const float* __restrict__ cl_sum, const float* __restrict__ counts,
    float* __restrict__ som_node) {
  int i = blockIdx.x * 256 + threadIdx.x;
  if (i >= Bb * 3 * Mm) return;
  int b = i / (3 * Mm), r = i % (3 * Mm), c = r / Mm, m = r % Mm;
  som_node[i] = cl_sum[(b * Mm + m) * 3 + c] / (counts[b * Mm + m] + 1e-5f);
}

__global__ __launch_bounds__(256) void build_h_kernel(
    const float* __restrict__ x, const float* __restrict__ sn,
    const float* __restrict__ som_node, const int* __restrict__ min_idx,
    float* __restrict__ h, int b0, int Pc) {
  int gid = blockIdx.x * 256 + threadIdx.x;
  if (gid >= 6 * Pc) return;
  int c = gid / Pc, pl = gid % Pc;
  int bl = pl / KN, i = pl % KN;
  int b = b0 + bl;
  int n = i % Nn;
  if (c < 3) {
    int idx = min_idx[b * KN + i];
    h[gid] = x[(b * 3 + c) * Nn + n] - som_node[(b * 3 + c) * Mm + idx];
  } else {
    h[gid] = sn[(b * 3 + (c - 3)) * Nn + n];
  }
}

// ---------------- generic f32 GEMM + bias/BN/ReLU (plain f32 [cout][P] out) ----------------
__global__ __launch_bounds__(256) void conv_gemm_kernel(
    const float* __restrict__ A, const float* __restrict__ W,
    const float* __restrict__ prm, float* __restrict__ out,
    int cin, int cout, int P) {
  __shared__ float Ws[16][68];
  __shared__ float As[16][64];
  int tid = threadIdx.x;
  int tx = tid % 16, ty = tid / 16;
  int p0 = blockIdx.x * 64, d0 = blockIdx.y * 64;
  float acc[4][4] = {};
  for (int k0 = 0; k0 < cin; k0 += 16) {
#pragma unroll
    for (int it = 0; it < 4; ++it) {
      int k = tid % 16, dl = tid / 16 + it * 16;
      float w = 0.f;
      if (k0 + k < cin) w = W[(size_t)(d0 + dl) * cin + k0 + k];
      Ws[k][dl] = w;
    }
#pragma unroll
    for (int it = 0; it < 4; ++it) {
      int pl = tid % 64, kl = tid / 64 + it * 4;
      float a = 0.f;
      if (k0 + kl < cin) a = A[(size_t)(k0 + kl) * P + p0 + pl];
      As[kl][pl] = a;
    }
    __syncthreads();
#pragma unroll
    for (int kk = 0; kk < 16; ++kk) {
      float4 av = *reinterpret_cast<const float4*>(&As[kk][tx * 4]);
      float4 wv = *reinterpret_cast<const float4*>(&Ws[kk][ty * 4]);
      float a4[4] = {av.x, av.y, av.z, av.w};
      float w4[4] = {wv.x, wv.y, wv.z, wv.w};
#pragma unroll
      for (int i2 = 0; i2 < 4; ++i2)
#pragma unroll
        for (int j = 0; j < 4; ++j) acc[i2][j] += w4[i2] * a4[j];
    }
    __syncthreads();
  }
#pragma unroll
  for (int i2 = 0; i2 < 4; ++i2) {
    int d = d0 + ty * 4 + i2;
    float bi = prm[d], ga = prm[cout + d], be = prm[2 * cout + d];
    float gs = ga * INV_BN_C;
#pragma unroll
    for (int j = 0; j < 4; ++j) {
      float v = (acc[i2][j] + bi) * gs + be;
      out[(size_t)d * P + p0 + tx * 4 + j] = v > 0.f ? v : 0.f;
    }
  }
}

// ---------------- f32 GEMM writing TRANSPOSED split-bf16 out [P][ostride] ----------------
__global__ __launch_bounds__(256) void conv_gemm_t_kernel(
    const float* __restrict__ A, const float* __restrict__ W,
    const float* __restrict__ prm, unsigned short* __restrict__ Ohi,
    unsigned short* __restrict__ Olo, int ostride, int oc0,
    int cin, int cout, int P) {
  __shared__ float Ws[16][68];
  __shared__ float As[16][64];
  int tid = threadIdx.x;
  int tx = tid % 16, ty = tid / 16;
  int p0 = blockIdx.x * 64, d0 = blockIdx.y * 64;
  float acc[4][4] = {};
  for (int k0 = 0; k0 < cin; k0 += 16) {
#pragma unroll
    for (int it = 0; it < 4; ++it) {
      int k = tid % 16, dl = tid / 16 + it * 16;
      float w = 0.f;
      if (k0 + k < cin) w = W[(size_t)(d0 + dl) * cin + k0 + k];
      Ws[k][dl] = w;
    }
#pragma unroll
    for (int it = 0; it < 4; ++it) {
      int pl = tid % 64, kl = tid / 64 + it * 4;
      float a = 0.f;
      if (k0 + kl < cin) a = A[(size_t)(k0 + kl) * P + p0 + pl];
      As[kl][pl] = a;
    }
    __syncthreads();
#pragma unroll
    for (int kk = 0; kk < 16; ++kk) {
      float4 av = *reinterpret_cast<const float4*>(&As[kk][tx * 4]);
      float4 wv = *reinterpret_cast<const float4*>(&Ws[kk][ty * 4]);
      float a4[4] = {av.x, av.y, av.z, av.w};
      float w4[4] = {wv.x, wv.y, wv.z, wv.w};
#pragma unroll
      for (int i2 = 0; i2 < 4; ++i2)
#pragma unroll
        for (int j = 0; j < 4; ++j) acc[i2][j] += w4[i2] * a4[j];
    }
    __syncthreads();
  }
#pragma unroll
  for (int i2 = 0; i2 < 4; ++i2) {
    int d = d0 + ty * 4 + i2;
    float bi = prm[d], ga = prm[cout + d], be = prm[2 * cout + d];
    float gs = ga * INV_BN_C;
#pragma unroll
    for (int j = 0; j < 4; ++j) {
      float v = (acc[i2][j] + bi) * gs + be;
      v = v > 0.f ? v : 0.f;
      size_t o = (size_t)(p0 + tx * 4 + j) * ostride + oc0 + d;
      unsigned short h = f2bf(v);
      Ohi[o] = h;
      Olo[o] = f2bf(v - bf2f(h));
    }
  }
}

// ---------------- split-bf16 MFMA GEMM (bf16x3 emulated fp32) ----------------
// C[d][p] = sum_k W[d][k] * A[p][k],  A stored transposed [P][astride] hi/lo bf16.
// Tile 128x128, BK=32, 4 waves (2x2), per-wave 4x4 frags of 16x16x32.
// OUT_F32=1: write f32 out [cout][P]; else write transposed split-bf16 [P][ostride].
template <int OUT_F32>
__global__ __launch_bounds__(256) void mfma3_gemm_kernel(
    const unsigned short* __restrict__ Ahi, const unsigned short* __restrict__ Alo,
    int astride, int ac0, int cin,
    const float* __restrict__ W, const float* __restrict__ prm, int cout,
    float* __restrict__ outF,
    unsigned short* __restrict__ Ohi, unsigned short* __restrict__ Olo,
    int ostride, int oc0, int P) {
  __shared__ unsigned short WhL[128][40];
  __shared__ unsigned short WlL[128][40];
  __shared__ unsigned short AhL[128][40];
  __shared__ unsigned short AlL[128][40];
  int tid = threadIdx.x;
  int lane = tid & 63, wave = tid >> 6;
  int wm = wave >> 1, wn = wave & 1;
  int lane15 = lane & 15, lh = lane >> 4;
  int p0 = blockIdx.x * 128, d0 = blockIdx.y * 128;

  f32x4 acc[4][4] = {};

  int srow = tid >> 1, shf = tid & 1;  // staging: 128 rows x 2 halves
  for (int k0 = 0; k0 < cin; k0 += 32) {
    // ---- stage W tile (f32 -> split bf16) ----
    {
      const float4* wp4 = reinterpret_cast<const float4*>(
          W + (size_t)(d0 + srow) * cin + k0 + shf * 16);
#pragma unroll
      for (int q = 0; q < 4; ++q) {
        float4 f = wp4[q];
        ushort4 hh, ll;
        hh.x = f2bf(f.x); ll.x = f2bf(f.x - bf2f(hh.x));
        hh.y = f2bf(f.y); ll.y = f2bf(f.y - bf2f(hh.y));
        hh.z = f2bf(f.z); ll.z = f2bf(f.z - bf2f(hh.z));
        hh.w = f2bf(f.w); ll.w = f2bf(f.w - bf2f(hh.w));
        *reinterpret_cast<ushort4*>(&WhL[srow][shf * 16 + q * 4]) = hh;
        *reinterpret_cast<ushort4*>(&WlL[srow][shf * 16 + q * 4]) = ll;
      }
    }
    // ---- stage act tile (already split bf16, transposed layout) ----
    {
      size_t base = (size_t)(p0 + srow) * astride + ac0 + k0 + shf * 16;
      const uint4* ph = reinterpret_cast<const uint4*>(Ahi + base);
      const uint4* pl = reinterpret_cast<const uint4*>(Alo + base);
      uint4 h0 = ph[0], h1 = ph[1];
      uint4 l0 = pl[0], l1 = pl[1];
      *reinterpret_cast<uint4*>(&AhL[srow][shf * 16 + 0]) = h0;
      *reinterpret_cast<uint4*>(&AhL[srow][shf * 16 + 8]) = h1;
      *reinterpret_cast<uint4*>(&AlL[srow][shf * 16 + 0]) = l0;
      *reinterpret_cast<uint4*>(&AlL[srow][shf * 16 + 8]) = l1;
    }
    __syncthreads();
    // ---- fragments ----
    bf16x8 wa_h[4], wa_l[4], xb_h[4], xb_l[4];
    int kof = lh * 8;
#pragma unroll
    for (int mi = 0; mi < 4; ++mi) {
      int r = wm * 64 + mi * 16 + lane15;
      wa_h[mi] = *reinterpret_cast<const bf16x8*>(&WhL[r][kof]);
      wa_l[mi] = *reinterpret_cast<const bf16x8*>(&WlL[r][kof]);
    }
#pragma unroll
    for (int ni = 0; ni < 4; ++ni) {
      int r = wn * 64 + ni * 16 + lane15;
      xb_h[ni] = *reinterpret_cast<const bf16x8*>(&AhL[r][kof]);
      xb_l[ni] = *reinterpret_cast<const bf16x8*>(&AlL[r][kof]);
    }
#pragma unroll
    for (int mi = 0; mi < 4; ++mi)
#pragma unroll
      for (int ni = 0; ni < 4; ++ni) {
        acc[mi][ni] = __builtin_amdgcn_mfma_f32_16x16x32_bf16(wa_h[mi], xb_h[ni], acc[mi][ni], 0, 0, 0);
        acc[mi][ni] = __builtin_amdgcn_mfma_f32_16x16x32_bf16(wa_h[mi], xb_l[ni], acc[mi][ni], 0, 0, 0);
        acc[mi][ni] = __builtin_amdgcn_mfma_f32_16x16x32_bf16(wa_l[mi], xb_h[ni], acc[mi][ni], 0, 0, 0);
      }
    __syncthreads();
  }
  // ---- epilogue: bias/BN/ReLU ----
#pragma unroll
  for (int mi = 0; mi < 4; ++mi) {
    int dbase = d0 + wm * 64 + mi * 16 + lh * 4;
#pragma unroll
    for (int ni = 0; ni < 4; ++ni) {
      int p = p0 + wn * 64 + ni * 16 + lane15;
      float vv[4];
#pragma unroll
      for (int r = 0; r < 4; ++r) {
        int d = dbase + r;
        float bi = prm[d], ga = prm[cout + d], be = prm[2 * cout + d];
        float v = (acc[mi][ni][r] + bi) * (ga * INV_BN_C) + be;
        vv[r] = v > 0.f ? v : 0.f;
      }
      if (OUT_F32) {
#pragma unroll
        for (int r = 0; r < 4; ++r) outF[(size_t)(dbase + r) * P + p] = vv[r];
      } else {
        ushort4 hh, ll;
        hh.x = f2bf(vv[0]); ll.x = f2bf(vv[0] - bf2f(hh.x));
        hh.y = f2bf(vv[1]); ll.y = f2bf(vv[1] - bf2f(hh.y));
        hh.z = f2bf(vv[2]); ll.z = f2bf(vv[2] - bf2f(hh.z));
        hh.w = f2bf(vv[3]); ll.w = f2bf(vv[3] - bf2f(hh.w));
        size_t o = (size_t)p * ostride + oc0 + dbase;
        *reinterpret_cast<ushort4*>(&Ohi[o]) = hh;
        *reinterpret_cast<ushort4*>(&Olo[o]) = ll;
      }
    }
  }
}

// ---------------- segment max ----------------
__global__ __launch_bounds__(256) void segmax_kernel(
    const float* __restrict__ first_out, const int* __restrict__ min_idx,
    float* __restrict__ node_feat, int b0, int Pc) {
  int d = blockIdx.x;
  int bl = blockIdx.y;
  int b = b0 + bl;
  __shared__ unsigned s_max[Mm];
  int t = threadIdx.x;
  if (t < Mm) s_max[t] = 0u;
  __syncthreads();
  const float* src = first_out + (size_t)d * Pc + (size_t)bl * KN;
  const int* mi = min_idx + b * KN;
  for (int i = t; i < KN; i += 256) {
    float v = src[i];
    int m = mi[i];
    atomicMax(&s_max[m], __float_as_uint(v));
  }
  __syncthreads();
  if (t < Mm) node_feat[((size_t)b * Mm + t) * 384 + d] = __uint_as_float(s_max[t]);
}

__global__ __launch_bounds__(256) void build_g_kernel(
    const float* __restrict__ som_node, const float* __restrict__ node_feat,
    const int* __restrict__ knnI, float* __restrict__ g, float* __restrict__ centerb) {
  const int P2 = Bb * Mm * SOMK;
  int gid = blockIdx.x * 256 + threadIdx.x;
  if (gid >= 387 * P2) return;
  int c = gid / P2, p = gid % P2;
  int b = p / (Mm * SOMK), r = p % (Mm * SOMK), m = r / SOMK, s = r % SOMK;
  int idx = knnI[(b * Mm + m) * SOMK + s];
  if (c < 3) {
    float sum = 0.f;
    for (int ss = 0; ss < SOMK; ++ss) {
      int ii = knnI[(b * Mm + m) * SOMK + ss];
      sum += som_node[(b * 3 + c) * Mm + ii];
    }
    float ctr = sum / 9.f;
    g[gid] = som_node[(b * 3 + c) * Mm + idx] - ctr;
    if (s == 0) centerb[(b * 3 + c) * Mm + m] = ctr;
  } else {
    g[gid] = node_feat[((size_t)b * Mm + idx) * 384 + (c - 3)];
  }
}

__global__ __launch_bounds__(256) void build_z_kernel(
    const float* __restrict__ centerb, const float* __restrict__ g3, float* __restrict__ z) {
  const int P3 = Bb * Mm;
  int gid = blockIdx.x * 256 + threadIdx.x;
  if (gid >= 515 * P3) return;
  int c = gid / P3, p = gid % P3;
  int b = p / Mm, m = p % Mm;
  if (c < 3) {
    z[gid] = centerb[(b * 3 + c) * Mm + m];
  } else {
    int d = c - 3;
    const float* src = g3 + (size_t)d * (Bb * Mm * SOMK) + b * (Mm * SOMK) + m * SOMK;
    float v = src[0];
    for (int s = 1; s < SOMK; ++s) v = fmaxf(v, src[s]);
    z[gid] = v;
  }
}

__global__ __launch_bounds__(256) void final_max_kernel(
    const float* __restrict__ z2, float* __restrict__ out) {
  int gid = blockIdx.x * 256 + threadIdx.x;
  if (gid >= Bb * 1024) return;
  int b = gid / 1024, d = gid % 1024;
  const float* src = z2 + (size_t)d * (Bb * Mm) + b * Mm;
  float v = src[0];
  for (int m = 1; m < Mm; ++m) v = fmaxf(v, src[m]);
  out[gid] = v;
}

extern "C" void kernel_launch(void* const* d_in, const int* in_sizes, int n_in,
                              void* d_out, int out_size, void* d_ws, size_t ws_size,
                              hipStream_t stream) {
  (void)in_sizes; (void)n_in; (void)out_size;
  const float* x = (const float*)d_in[0];
  const float* sn = (const float*)d_in[1];
  const float* node = (const float*)d_in[2];
  const int* knnI = (const int*)d_in[3];
  const float* Wfp0 = (const float*)d_in[4];  const float* Pfp0 = (const float*)d_in[5];
  const float* Wfp1 = (const float*)d_in[6];  const float* Pfp1 = (const float*)d_in[7];
  const float* Wfp2 = (const float*)d_in[8];  const float* Pfp2 = (const float*)d_in[9];
  const float* Wfp3 = (const float*)d_in[10]; const float* Pfp3 = (const float*)d_in[11];
  const float* Wk0  = (const float*)d_in[12]; const float* Pk0  = (const float*)d_in[13];
  const float* Wk1  = (const float*)d_in[14]; const float* Pk1  = (const float*)d_in[15];
  const float* Wf0  = (const float*)d_in[16]; const float* Pf0  = (const float*)d_in[17];
  const float* Wf1  = (const float*)d_in[18]; const float* Pf1  = (const float*)d_in[19];
  float* out = (float*)d_out;

  char* ws = (char*)d_ws;
  size_t off = 0;
  auto alloc = [&](size_t bytes) -> void* {
    void* p = ws + off;
    off += (bytes + 255) & ~(size_t)255;
    return p;
  };
  float* counts    = (float*)alloc(512 * 4);
  float* cl_sum    = (float*)alloc(1536 * 4);
  float* som_node  = (float*)alloc(1536 * 4);
  float* centerb   = (float*)alloc(1536 * 4);
  int*   min_idx   = (int*)alloc((size_t)Bb * KN * 4);
  float* node_feat = (float*)alloc((size_t)Bb * Mm * 384 * 4);
  float* g   = (float*)alloc(387ull * 4608 * 4);
  float* g2  = (float*)alloc(512ull * 4608 * 4);
  float* g3  = (float*)alloc(512ull * 4608 * 4);
  float* zb  = (float*)alloc(515ull * 512 * 4);
  float* z1  = (float*)alloc(768ull * 512 * 4);
  float* z2  = (float*)alloc(1024ull * 512 * 4);
  size_t small_end = off;

  // per-chunk: h(6*4) + A1 hi/lo (320*2*2) + y1 hi/lo (128*2*2) + fo(384*4) = 3352 B/pt
  size_t per_b = 838ull * KN * 4;
  int Bc = 1;
  if (small_end + 8 * per_b + 4096 <= ws_size) Bc = 8;
  else if (small_end + 4 * per_b + 4096 <= ws_size) Bc = 4;
  else if (small_end + 2 * per_b + 4096 <= ws_size) Bc = 2;
  int Pc = Bc * KN;
  float* h = (float*)alloc(6ull * Pc * 4);
  unsigned short* A1hi = (unsigned short*)alloc(320ull * Pc * 2);
  unsigned short* A1lo = (unsigned short*)alloc(320ull * Pc * 2);
  unsigned short* y1hi = (unsigned short*)alloc(128ull * Pc * 2);
  unsigned short* y1lo = (unsigned short*)alloc(128ull * Pc * 2);
  float* fo = (float*)alloc(384ull * Pc * 4);

  hipMemsetAsync(counts, 0, 512 * 4, stream);
  hipMemsetAsync(cl_sum, 0, 1536 * 4, stream);
  som_assign_kernel<<<dim3(Nn / 256, Bb), 256, 0, stream>>>(x, node, min_idx, counts, cl_sum);
  som_node_kernel<<<6, 256, 0, stream>>>(cl_sum, counts, som_node);

  for (int b0 = 0; b0 < Bb; b0 += Bc) {
    build_h_kernel<<<(6 * Pc) / 256, 256, 0, stream>>>(x, sn, som_node, min_idx, h, b0, Pc);
    // fp0: f32 GEMM (cin=6) -> transposed split-bf16 y0 into A1 cols 0..63
    conv_gemm_t_kernel<<<dim3(Pc / 64, 1), 256, 0, stream>>>(
        h, Wfp0, Pfp0, A1hi, A1lo, 320, 0, 6, 64, Pc);
    // fp1: 64 -> 128, out y1
    mfma3_gemm_kernel<0><<<dim3(Pc / 128, 1), 256, 0, stream>>>(
        A1hi, A1lo, 320, 0, 64, Wfp1, Pfp1, 128, nullptr, y1hi, y1lo, 128, 0, Pc);
    // fp2: 128 -> 256, out into A1 cols 64..319
    mfma3_gemm_kernel<0><<<dim3(Pc / 128, 2), 256, 0, stream>>>(
        y1hi, y1lo, 128, 0, 128, Wfp2, Pfp2, 256, nullptr, A1hi, A1lo, 320, 64, Pc);
    // fp3: 320 -> 384, out f32 fo [384][Pc]
    mfma3_gemm_kernel<1><<<dim3(Pc / 128, 3), 256, 0, stream>>>(
        A1hi, A1lo, 320, 0, 320, Wfp3, Pfp3, 384, fo, nullptr, nullptr, 0, 0, Pc);
    segmax_kernel<<<dim3(384, Bc), 256, 0, stream>>>(fo, min_idx, node_feat, b0, Pc);
  }

  build_g_kernel<<<(387 * 4608) / 256, 256, 0, stream>>>(som_node, node_feat, knnI, g, centerb);
  conv_gemm_kernel<<<dim3(4608 / 64, 8), 256, 0, stream>>>(g, Wk0, Pk0, g2, 387, 512, 4608);
  conv_gemm_kernel<<<dim3(4608 / 64, 8), 256, 0, stream>>>(g2, Wk1, Pk1, g3, 512, 512, 4608);
  build_z_kernel<<<(515 * 512 + 255) / 256, 256, 0, stream>>>(centerb, g3, zb);
  conv_gemm_kernel<<<dim3(8, 12), 256, 0, stream>>>(zb, Wf0, Pf0, z1, 515, 768, 512);
  conv_gemm_kernel<<<dim3(8, 16), 256, 0, stream>>>(z1, Wf1, Pf1, z2, 768, 1024, 512);
  final_max_kernel<<<32, 256, 0, stream>>>(z2, out);
}

// Round 4
// 892.879 us; speedup vs baseline: 1.8179x; 1.1950x over previous
//
#include <hip/hip_runtime.h>

#define Nn 8192
#define Mm 64
#define Bb 8
#define Kk 3
#define SOMK 9
#define KN (Kk * Nn)  // 24576

__device__ __constant__ float INV_BN_C = 0.9999950000374997f;

typedef short bf16x8 __attribute__((ext_vector_type(8)));
typedef float f32x4 __attribute__((ext_vector_type(4)));

__device__ __forceinline__ unsigned short f2bf(float f) {
  unsigned int u = __float_as_uint(f);
  return (unsigned short)((u + 0x7fffu + ((u >> 16) & 1u)) >> 16);
}
__device__ __forceinline__ float bf2f(unsigned short h) {
  return __uint_as_float(((unsigned int)h) << 16);
}

// ---------------- SOM assignment: top-3 nearest nodes per point ----------------
__global__ __launch_bounds__(256) void som_assign_kernel(
    const float* __restrict__ x, const float* __restrict__ node,
    int* __restrict__ min_idx, float* __restrict__ counts, float* __restrict__ cl_sum) {
  int b = blockIdx.y;
  int n = blockIdx.x * 256 + threadIdx.x;
  __shared__ float nd[3][Mm];
  __shared__ float s_cnt[Mm];
  __shared__ float s_sum[Mm][3];
  int t = threadIdx.x;
  if (t < 192) nd[t / 64][t % 64] = node[(b * 3 + t / 64) * Mm + (t % 64)];
  if (t < Mm) { s_cnt[t] = 0.f; s_sum[t][0] = 0.f; s_sum[t][1] = 0.f; s_sum[t][2] = 0.f; }
  __syncthreads();
  float x0 = x[(b * 3 + 0) * Nn + n];
  float x1 = x[(b * 3 + 1) * Nn + n];
  float x2 = x[(b * 3 + 2) * Nn + n];
  float b0 = 1e30f, b1 = 1e30f, b2 = 1e30f;
  int j0 = 0, j1 = 0, j2 = 0;
  for (int m = 0; m < Mm; ++m) {
    float dx = x0 - nd[0][m];
    float dy = x1 - nd[1][m];
    float dz = x2 - nd[2][m];
    float d = __fadd_rn(__fadd_rn(__fmul_rn(dx, dx), __fmul_rn(dy, dy)), __fmul_rn(dz, dz));
    if (d < b0)      { b2 = b1; j2 = j1; b1 = b0; j1 = j0; b0 = d; j0 = m; }
    else if (d < b1) { b2 = b1; j2 = j1; b1 = d; j1 = m; }
    else if (d < b2) { b2 = d; j2 = m; }
  }
  min_idx[b * KN + 0 * Nn + n] = j0;
  min_idx[b * KN + 1 * Nn + n] = j1;
  min_idx[b * KN + 2 * Nn + n] = j2;
  atomicAdd(&s_cnt[j0], 1.f);
  atomicAdd(&s_cnt[j1], 1.f);
  atomicAdd(&s_cnt[j2], 1.f);
  atomicAdd(&s_sum[j0][0], x0); atomicAdd(&s_sum[j0][1], x1); atomicAdd(&s_sum[j0][2], x2);
  atomicAdd(&s_sum[j1][0], x0); atomicAdd(&s_sum[j1][1], x1); atomicAdd(&s_sum[j1][2], x2);
  atomicAdd(&s_sum[j2][0], x0); atomicAdd(&s_sum[j2][1], x1); atomicAdd(&s_sum[j2][2], x2);
  __syncthreads();
  if (t < Mm) {
    atomicAdd(&counts[b * Mm + t], s_cnt[t]);
    atomicAdd(&cl_sum[(b * Mm + t) * 3 + 0], s_sum[t][0]);
    atomicAdd(&cl_sum[(b * Mm + t) * 3 + 1], s_sum[t][1]);
    atomicAdd(&cl_sum[(b * Mm + t) * 3 + 2], s_sum[t][2]);
  }
}

__global__ __launch_bounds__(256) void som_node_kernel(
    const float* __restrict__ cl_sum, const float* __restrict__ counts,
    float* __restrict__ som_node) {
  int i = blockIdx.x * 256 + threadIdx.x;
  if (i >= Bb * 3 * Mm) return;
  int b = i / (3 * Mm), r = i % (3 * Mm), c = r / Mm, m = r % Mm;
  som_node[i] = cl_sum[(b * Mm + m) * 3 + c] / (counts[b * Mm + m] + 1e-5f);
}

__global__ __launch_bounds__(256) void build_h_kernel(
    const float* __restrict__ x, const float* __restrict__ sn,
    const float* __restrict__ som_node, const int* __restrict__ min_idx,
    float* __restrict__ h, int b0, int Pc) {
  int gid = blockIdx.x * 256 + threadIdx.x;
  if (gid >= 6 * Pc) return;
  int c = gid / Pc, pl = gid % Pc;
  int bl = pl / KN, i = pl % KN;
  int b = b0 + bl;
  int n = i % Nn;
  if (c < 3) {
    int idx = min_idx[b * KN + i];
    h[gid] = x[(b * 3 + c) * Nn + n] - som_node[(b * 3 + c) * Mm + idx];
  } else {
    h[gid] = sn[(b * 3 + (c - 3)) * Nn + n];
  }
}

// ---------------- weight pre-split: f32 [cout][cin] -> padded hi/lo bf16 [cout][cinp] ----------------
struct WsplitDesc {
  const float* W; unsigned short* hi; unsigned short* lo; int cin, cinp, total;
};
struct WsplitArgs { WsplitDesc d[7]; };
__global__ __launch_bounds__(256) void split_w_kernel(WsplitArgs a) {
  WsplitDesc dd = a.d[blockIdx.y];
  for (int gid = blockIdx.x * 256 + threadIdx.x; gid < dd.total; gid += gridDim.x * 256) {
    int r = gid / dd.cinp, c = gid % dd.cinp;
    float v = (c < dd.cin) ? dd.W[(size_t)r * dd.cin + c] : 0.f;
    unsigned short h = f2bf(v);
    dd.hi[gid] = h;
    dd.lo[gid] = f2bf(v - bf2f(h));
  }
}

// ---------------- f32 GEMM (cin=6) writing TRANSPOSED split-bf16 out [P][ostride] ----------------
__global__ __launch_bounds__(256) void conv_gemm_t_kernel(
    const float* __restrict__ A, const float* __restrict__ W,
    const float* __restrict__ prm, unsigned short* __restrict__ Ohi,
    unsigned short* __restrict__ Olo, int ostride, int oc0,
    int cin, int cout, int P) {
  __shared__ float Ws[16][68];
  __shared__ float As[16][64];
  int tid = threadIdx.x;
  int tx = tid % 16, ty = tid / 16;
  int p0 = blockIdx.x * 64, d0 = blockIdx.y * 64;
  float acc[4][4] = {};
  for (int k0 = 0; k0 < cin; k0 += 16) {
#pragma unroll
    for (int it = 0; it < 4; ++it) {
      int k = tid % 16, dl = tid / 16 + it * 16;
      float w = 0.f;
      if (k0 + k < cin) w = W[(size_t)(d0 + dl) * cin + k0 + k];
      Ws[k][dl] = w;
    }
#pragma unroll
    for (int it = 0; it < 4; ++it) {
      int pl = tid % 64, kl = tid / 64 + it * 4;
      float a = 0.f;
      if (k0 + kl < cin) a = A[(size_t)(k0 + kl) * P + p0 + pl];
      As[kl][pl] = a;
    }
    __syncthreads();
#pragma unroll
    for (int kk = 0; kk < 16; ++kk) {
      float4 av = *reinterpret_cast<const float4*>(&As[kk][tx * 4]);
      float4 wv = *reinterpret_cast<const float4*>(&Ws[kk][ty * 4]);
      float a4[4] = {av.x, av.y, av.z, av.w};
      float w4[4] = {wv.x, wv.y, wv.z, wv.w};
#pragma unroll
      for (int i2 = 0; i2 < 4; ++i2)
#pragma unroll
        for (int j = 0; j < 4; ++j) acc[i2][j] += w4[i2] * a4[j];
    }
    __syncthreads();
  }
#pragma unroll
  for (int i2 = 0; i2 < 4; ++i2) {
    int d = d0 + ty * 4 + i2;
    float bi = prm[d], ga = prm[cout + d], be = prm[2 * cout + d];
    float gs = ga * INV_BN_C;
#pragma unroll
    for (int j = 0; j < 4; ++j) {
      float v = (acc[i2][j] + bi) * gs + be;
      v = v > 0.f ? v : 0.f;
      size_t o = (size_t)(p0 + tx * 4 + j) * ostride + oc0 + d;
      unsigned short hh = f2bf(v);
      Ohi[o] = hh;
      Olo[o] = f2bf(v - bf2f(hh));
    }
  }
}

// ---------------- split-bf16 MFMA GEMM (bf16x3 emulated fp32) ----------------
// C[d][p] = sum_k W[d][k]*A[p][k]. A transposed split-bf16 [P][astride]; W pre-split [cout][wstride].
// Tile 128x128, BK=32, 4 waves (2x2), 4x4 frags of 16x16x32.
// OUT: 0 = transposed split-bf16 out; 1 = f32 [cout][P]; 2 = fused segment-max partials.
template <int OUT>
__global__ __launch_bounds__(256) void mfma3_gemm_kernel(
    const unsigned short* __restrict__ Ahi, const unsigned short* __restrict__ Alo,
    int astride, int ac0, int cin,
    const unsigned short* __restrict__ Whi, const unsigned short* __restrict__ Wlo,
    int wstride, const float* __restrict__ prm, int cout,
    float* __restrict__ outF,
    unsigned short* __restrict__ Ohi, unsigned short* __restrict__ Olo,
    int ostride, int oc0, int P,
    float* __restrict__ partial, const int* __restrict__ mi_chunk, int PBN) {
  __shared__ unsigned short smem[4 * 128 * 40];  // 40960 B
  typedef unsigned short RowT[40];
  RowT* WhL = (RowT*)smem;
  RowT* WlL = (RowT*)(smem + 128 * 40);
  RowT* AhL = (RowT*)(smem + 2 * 128 * 40);
  RowT* AlL = (RowT*)(smem + 3 * 128 * 40);

  int tid = threadIdx.x;
  int lane = tid & 63, wave = tid >> 6;
  int wm = wave >> 1, wn = wave & 1;
  int lane15 = lane & 15, lh = lane >> 4;
  int p0 = blockIdx.x * 128, d0 = blockIdx.y * 128;

  f32x4 acc[4][4] = {};

  int srow = tid >> 1, shf = tid & 1;
  for (int k0 = 0; k0 < cin; k0 += 32) {
    {
      size_t wb = (size_t)(d0 + srow) * wstride + k0 + shf * 16;
      const uint4* ph = reinterpret_cast<const uint4*>(Whi + wb);
      const uint4* pl = reinterpret_cast<const uint4*>(Wlo + wb);
      uint4 h0 = ph[0], h1 = ph[1], l0 = pl[0], l1 = pl[1];
      *reinterpret_cast<uint4*>(&WhL[srow][shf * 16 + 0]) = h0;
      *reinterpret_cast<uint4*>(&WhL[srow][shf * 16 + 8]) = h1;
      *reinterpret_cast<uint4*>(&WlL[srow][shf * 16 + 0]) = l0;
      *reinterpret_cast<uint4*>(&WlL[srow][shf * 16 + 8]) = l1;
    }
    {
      size_t base = (size_t)(p0 + srow) * astride + ac0 + k0 + shf * 16;
      const uint4* ph = reinterpret_cast<const uint4*>(Ahi + base);
      const uint4* pl = reinterpret_cast<const uint4*>(Alo + base);
      uint4 h0 = ph[0], h1 = ph[1], l0 = pl[0], l1 = pl[1];
      *reinterpret_cast<uint4*>(&AhL[srow][shf * 16 + 0]) = h0;
      *reinterpret_cast<uint4*>(&AhL[srow][shf * 16 + 8]) = h1;
      *reinterpret_cast<uint4*>(&AlL[srow][shf * 16 + 0]) = l0;
      *reinterpret_cast<uint4*>(&AlL[srow][shf * 16 + 8]) = l1;
    }
    __syncthreads();
    bf16x8 wa_h[4], wa_l[4], xb_h[4], xb_l[4];
    int kof = lh * 8;
#pragma unroll
    for (int mi = 0; mi < 4; ++mi) {
      int r = wm * 64 + mi * 16 + lane15;
      wa_h[mi] = *reinterpret_cast<const bf16x8*>(&WhL[r][kof]);
      wa_l[mi] = *reinterpret_cast<const bf16x8*>(&WlL[r][kof]);
    }
#pragma unroll
    for (int ni = 0; ni < 4; ++ni) {
      int r = wn * 64 + ni * 16 + lane15;
      xb_h[ni] = *reinterpret_cast<const bf16x8*>(&AhL[r][kof]);
      xb_l[ni] = *reinterpret_cast<const bf16x8*>(&AlL[r][kof]);
    }
#pragma unroll
    for (int mi = 0; mi < 4; ++mi)
#pragma unroll
      for (int ni = 0; ni < 4; ++ni) {
        acc[mi][ni] = __builtin_amdgcn_mfma_f32_16x16x32_bf16(wa_h[mi], xb_h[ni], acc[mi][ni], 0, 0, 0);
        acc[mi][ni] = __builtin_amdgcn_mfma_f32_16x16x32_bf16(wa_h[mi], xb_l[ni], acc[mi][ni], 0, 0, 0);
        acc[mi][ni] = __builtin_amdgcn_mfma_f32_16x16x32_bf16(wa_l[mi], xb_h[ni], acc[mi][ni], 0, 0, 0);
      }
    __syncthreads();
  }

  if (OUT == 2) {
    // fused segment-max: LDS-reduce tile over p grouped by cluster m, write partials
    float* s_nf = (float*)smem;                 // [64 m][132] padded, 33792 B
    int* s_mi = (int*)(smem + 16896);           // [128], after s_nf
    for (int i = tid; i < 64 * 132; i += 256) s_nf[i] = 0.f;
    if (tid < 128) s_mi[tid] = mi_chunk[p0 + tid];
    __syncthreads();
    int mloc[4];
#pragma unroll
    for (int ni = 0; ni < 4; ++ni) mloc[ni] = s_mi[wn * 64 + ni * 16 + lane15];
#pragma unroll
    for (int mi = 0; mi < 4; ++mi) {
      int dbase = wm * 64 + mi * 16 + lh * 4;
#pragma unroll
      for (int ni = 0; ni < 4; ++ni) {
        int m = mloc[ni];
#pragma unroll
        for (int r = 0; r < 4; ++r) {
          int d = d0 + dbase + r;
          float bi = prm[d], ga = prm[cout + d], be = prm[2 * cout + d];
          float v = (acc[mi][ni][r] + bi) * (ga * INV_BN_C) + be;
          if (v > 0.f)
            atomicMax((unsigned*)&s_nf[m * 132 + dbase + r], __float_as_uint(v));
        }
      }
    }
    __syncthreads();
    float* pout = partial + ((size_t)(blockIdx.y * PBN + blockIdx.x) * 64) * 128;
    for (int i = tid; i < 8192; i += 256) {
      int m = i >> 7, dl = i & 127;
      pout[i] = s_nf[m * 132 + dl];
    }
    return;
  }

#pragma unroll
  for (int mi = 0; mi < 4; ++mi) {
    int dbase = d0 + wm * 64 + mi * 16 + lh * 4;
#pragma unroll
    for (int ni = 0; ni < 4; ++ni) {
      int p = p0 + wn * 64 + ni * 16 + lane15;
      float vv[4];
#pragma unroll
      for (int r = 0; r < 4; ++r) {
        int d = dbase + r;
        float bi = prm[d], ga = prm[cout + d], be = prm[2 * cout + d];
        float v = (acc[mi][ni][r] + bi) * (ga * INV_BN_C) + be;
        vv[r] = v > 0.f ? v : 0.f;
      }
      if (OUT == 1) {
#pragma unroll
        for (int r = 0; r < 4; ++r) outF[(size_t)(dbase + r) * P + p] = vv[r];
      } else {
        ushort4 hh, ll;
        hh.x = f2bf(vv[0]); ll.x = f2bf(vv[0] - bf2f(hh.x));
        hh.y = f2bf(vv[1]); ll.y = f2bf(vv[1] - bf2f(hh.y));
        hh.z = f2bf(vv[2]); ll.z = f2bf(vv[2] - bf2f(hh.z));
        hh.w = f2bf(vv[3]); ll.w = f2bf(vv[3] - bf2f(hh.w));
        size_t o = (size_t)p * ostride + oc0 + dbase;
        *reinterpret_cast<ushort4*>(&Ohi[o]) = hh;
        *reinterpret_cast<ushort4*>(&Olo[o]) = ll;
      }
    }
  }
}

// ---------------- reduce partials -> node_feat [B*M][384] ----------------
__global__ __launch_bounds__(256) void reduce_nf_kernel(
    const float* __restrict__ part, float* __restrict__ nf, int PBN, int b0, int Bc) {
  int gid = blockIdx.x * 256 + threadIdx.x;  // over 3*Bc*64*128
  int yblk = gid / (Bc * 8192);
  int rem = gid % (Bc * 8192);
  int bl = rem / 8192, r = rem % 8192;
  int m = r >> 7, dl = r & 127;
  float v = 0.f;
  const float* src = part + ((size_t)(yblk * PBN + bl * 192) * 64 + m) * 128 + dl;
  for (int j = 0; j < 192; ++j) v = fmaxf(v, src[(size_t)j * 8192]);
  nf[((size_t)((b0 + bl) * Mm + m)) * 384 + yblk * 128 + dl] = v;
}

// ---------------- build g transposed split-bf16 [4608][416]; also centerb ----------------
__global__ __launch_bounds__(256) void build_g_t_kernel(
    const float* __restrict__ som_node, const float* __restrict__ node_feat,
    const int* __restrict__ knnI, unsigned short* __restrict__ ghi,
    unsigned short* __restrict__ glo, float* __restrict__ centerb) {
  int p = blockIdx.x;  // b*576 + m*9 + s
  int b = p / (Mm * SOMK), r = p % (Mm * SOMK), m = r / SOMK, s = r % SOMK;
  int t = threadIdx.x;
  __shared__ int nb[SOMK];
  __shared__ float ctr[3];
  if (t < SOMK) nb[t] = knnI[(b * Mm + m) * SOMK + t];
  __syncthreads();
  if (t < 3) {
    float sum = 0.f;
    for (int ss = 0; ss < SOMK; ++ss) sum += som_node[(b * 3 + t) * Mm + nb[ss]];
    float c = sum / 9.f;
    ctr[t] = c;
    if (s == 0) centerb[(b * 3 + t) * Mm + m] = c;
  }
  __syncthreads();
  int idx = nb[s];
  for (int c = t; c < 416; c += 256) {
    float v;
    if (c < 3) v = som_node[(b * 3 + c) * Mm + idx] - ctr[c];
    else if (c < 387) v = node_feat[((size_t)(b * Mm + idx)) * 384 + (c - 3)];
    else v = 0.f;
    unsigned short hh = f2bf(v);
    size_t o = (size_t)p * 416 + c;
    ghi[o] = hh;
    glo[o] = f2bf(v - bf2f(hh));
  }
}

// ---------------- build z transposed split-bf16 [512][544] from g3 f32 [512][4608] ----------------
__global__ __launch_bounds__(256) void build_z_t_kernel(
    const float* __restrict__ centerb, const float* __restrict__ g3,
    unsigned short* __restrict__ zhi, unsigned short* __restrict__ zlo) {
  int p = blockIdx.x;  // b*64 + m
  int b = p >> 6, m = p & 63;
  int t = threadIdx.x;
  for (int c = t; c < 544; c += 256) {
    float v;
    if (c < 3) {
      v = centerb[(b * 3 + c) * Mm + m];
    } else if (c < 515) {
      const float* src = g3 + (size_t)(c - 3) * (Bb * Mm * SOMK) + b * (Mm * SOMK) + m * SOMK;
      v = src[0];
      for (int s = 1; s < SOMK; ++s) v = fmaxf(v, src[s]);
    } else {
      v = 0.f;
    }
    unsigned short hh = f2bf(v);
    size_t o = (size_t)p * 544 + c;
    zhi[o] = hh;
    zlo[o] = f2bf(v - bf2f(hh));
  }
}

__global__ __launch_bounds__(256) void final_max_kernel(
    const float* __restrict__ z2, float* __restrict__ out) {
  int gid = blockIdx.x * 256 + threadIdx.x;
  if (gid >= Bb * 1024) return;
  int b = gid / 1024, d = gid % 1024;
  const float* src = z2 + (size_t)d * (Bb * Mm) + b * Mm;
  float v = src[0];
  for (int m = 1; m < Mm; ++m) v = fmaxf(v, src[m]);
  out[gid] = v;
}

extern "C" void kernel_launch(void* const* d_in, const int* in_sizes, int n_in,
                              void* d_out, int out_size, void* d_ws, size_t ws_size,
                              hipStream_t stream) {
  (void)in_sizes; (void)n_in; (void)out_size;
  const float* x = (const float*)d_in[0];
  const float* sn = (const float*)d_in[1];
  const float* node = (const float*)d_in[2];
  const int* knnI = (const int*)d_in[3];
  const float* Wfp0 = (const float*)d_in[4];  const float* Pfp0 = (const float*)d_in[5];
  const float* Wfp1 = (const float*)d_in[6];  const float* Pfp1 = (const float*)d_in[7];
  const float* Wfp2 = (const float*)d_in[8];  const float* Pfp2 = (const float*)d_in[9];
  const float* Wfp3 = (const float*)d_in[10]; const float* Pfp3 = (const float*)d_in[11];
  const float* Wk0  = (const float*)d_in[12]; const float* Pk0  = (const float*)d_in[13];
  const float* Wk1  = (const float*)d_in[14]; const float* Pk1  = (const float*)d_in[15];
  const float* Wf0  = (const float*)d_in[16]; const float* Pf0  = (const float*)d_in[17];
  const float* Wf1  = (const float*)d_in[18]; const float* Pf1  = (const float*)d_in[19];
  float* out = (float*)d_out;

  char* ws = (char*)d_ws;
  size_t off = 0;
  auto alloc = [&](size_t bytes) -> void* {
    void* p = ws + off;
    off += (bytes + 255) & ~(size_t)255;
    return p;
  };
  float* counts    = (float*)alloc(512 * 4);
  float* cl_sum    = (float*)alloc(1536 * 4);
  float* som_node  = (float*)alloc(1536 * 4);
  float* centerb   = (float*)alloc(1536 * 4);
  int*   min_idx   = (int*)alloc((size_t)Bb * KN * 4);
  float* node_feat = (float*)alloc((size_t)Bb * Mm * 384 * 4);

  // pre-split weight buffers (hi/lo, padded cin)
  const int cinp_fp1 = 64, cinp_fp2 = 128, cinp_fp3 = 320;
  const int cinp_k0 = 416, cinp_k1 = 512, cinp_f0 = 544, cinp_f1 = 768;
  unsigned short *Wh[7], *Wl[7];
  int wtot[7] = {128 * 64, 256 * 128, 384 * 320, 512 * 416, 512 * 512, 768 * 544, 1024 * 768};
  for (int i = 0; i < 7; ++i) {
    Wh[i] = (unsigned short*)alloc((size_t)wtot[i] * 2);
    Wl[i] = (unsigned short*)alloc((size_t)wtot[i] * 2);
  }

  unsigned short* ghi  = (unsigned short*)alloc(4608ull * 416 * 2);
  unsigned short* glo  = (unsigned short*)alloc(4608ull * 416 * 2);
  unsigned short* g2hi = (unsigned short*)alloc(4608ull * 512 * 2);
  unsigned short* g2lo = (unsigned short*)alloc(4608ull * 512 * 2);
  float* g3 = (float*)alloc(512ull * 4608 * 4);
  unsigned short* zbhi = (unsigned short*)alloc(512ull * 544 * 2);
  unsigned short* zblo = (unsigned short*)alloc(512ull * 544 * 2);
  unsigned short* z1hi = (unsigned short*)alloc(512ull * 768 * 2);
  unsigned short* z1lo = (unsigned short*)alloc(512ull * 768 * 2);
  float* z2 = (float*)alloc(1024ull * 512 * 4);
  size_t small_end = off;

  // per-chunk: h 24 B/pt + A1 hi/lo 1280 + y1 hi/lo 512 + partial 768 = 2584 B/pt
  size_t per_b = 2584ull * KN;
  int Bc = 1;
  if (small_end + 8 * per_b + 4096 <= ws_size) Bc = 8;
  else if (small_end + 4 * per_b + 4096 <= ws_size) Bc = 4;
  else if (small_end + 2 * per_b + 4096 <= ws_size) Bc = 2;
  int Pc = Bc * KN;
  int PBN = Pc / 128;
  float* h = (float*)alloc(6ull * Pc * 4);
  unsigned short* A1hi = (unsigned short*)alloc(320ull * Pc * 2);
  unsigned short* A1lo = (unsigned short*)alloc(320ull * Pc * 2);
  unsigned short* y1hi = (unsigned short*)alloc(128ull * Pc * 2);
  unsigned short* y1lo = (unsigned short*)alloc(128ull * Pc * 2);
  float* Ppart = (float*)alloc(3ull * PBN * 64 * 128 * 4);

  hipMemsetAsync(counts, 0, 512 * 4, stream);
  hipMemsetAsync(cl_sum, 0, 1536 * 4, stream);
  som_assign_kernel<<<dim3(Nn / 256, Bb), 256, 0, stream>>>(x, node, min_idx, counts, cl_sum);
  som_node_kernel<<<6, 256, 0, stream>>>(cl_sum, counts, som_node);

  {
    WsplitArgs wa;
    const float* Wsrc[7] = {Wfp1, Wfp2, Wfp3, Wk0, Wk1, Wf0, Wf1};
    int cins[7] = {64, 128, 320, 387, 512, 515, 768};
    int cinps[7] = {cinp_fp1, cinp_fp2, cinp_fp3, cinp_k0, cinp_k1, cinp_f0, cinp_f1};
    for (int i = 0; i < 7; ++i)
      wa.d[i] = WsplitDesc{Wsrc[i], Wh[i], Wl[i], cins[i], cinps[i], wtot[i]};
    split_w_kernel<<<dim3(128, 7), 256, 0, stream>>>(wa);
  }

  for (int b0 = 0; b0 < Bb; b0 += Bc) {
    build_h_kernel<<<(6 * Pc) / 256, 256, 0, stream>>>(x, sn, som_node, min_idx, h, b0, Pc);
    // fp0: f32 GEMM (cin=6) -> transposed split-bf16 into A1 cols 0..63
    conv_gemm_t_kernel<<<dim3(Pc / 64, 1), 256, 0, stream>>>(
        h, Wfp0, Pfp0, A1hi, A1lo, 320, 0, 6, 64, Pc);
    // fp1: 64 -> 128
    mfma3_gemm_kernel<0><<<dim3(Pc / 128, 1), 256, 0, stream>>>(
        A1hi, A1lo, 320, 0, 64, Wh[0], Wl[0], cinp_fp1, Pfp1, 128,
        nullptr, y1hi, y1lo, 128, 0, Pc, nullptr, nullptr, 0);
    // fp2: 128 -> 256 into A1 cols 64..319
    mfma3_gemm_kernel<0><<<dim3(Pc / 128, 2), 256, 0, stream>>>(
        y1hi, y1lo, 128, 0, 128, Wh[1], Wl[1], cinp_fp2, Pfp2, 256,
        nullptr, A1hi, A1lo, 320, 64, Pc, nullptr, nullptr, 0);
    // fp3: 320 -> 384, fused segment-max partials
    mfma3_gemm_kernel<2><<<dim3(PBN, 3), 256, 0, stream>>>(
        A1hi, A1lo, 320, 0, 320, Wh[2], Wl[2], cinp_fp3, Pfp3, 384,
        nullptr, nullptr, nullptr, 0, 0, Pc, Ppart, min_idx + b0 * KN, PBN);
    reduce_nf_kernel<<<96 * Bc, 256, 0, stream>>>(Ppart, node_feat, PBN, b0, Bc);
  }

  build_g_t_kernel<<<4608, 256, 0, stream>>>(som_node, node_feat, knnI, ghi, glo, centerb);
  // knn0: 416 -> 512
  mfma3_gemm_kernel<0><<<dim3(36, 4), 256, 0, stream>>>(
      ghi, glo, 416, 0, 416, Wh[3], Wl[3], cinp_k0, Pk0, 512,
      nullptr, g2hi, g2lo, 512, 0, 4608, nullptr, nullptr, 0);
  // knn1: 512 -> 512, f32 out g3
  mfma3_gemm_kernel<1><<<dim3(36, 4), 256, 0, stream>>>(
      g2hi, g2lo, 512, 0, 512, Wh[4], Wl[4], cinp_k1, Pk1, 512,
      g3, nullptr, nullptr, 0, 0, 4608, nullptr, nullptr, 0);
  build_z_t_kernel<<<512, 256, 0, stream>>>(centerb, g3, zbhi, zblo);
  // fin0: 544 -> 768
  mfma3_gemm_kernel<0><<<dim3(4, 6), 256, 0, stream>>>(
      zbhi, zblo, 544, 0, 544, Wh[5], Wl[5], cinp_f0, Pf0, 768,
      nullptr, z1hi, z1lo, 768, 0, 512, nullptr, nullptr, 0);
  // fin1: 768 -> 1024, f32 out z2
  mfma3_gemm_kernel<1><<<dim3(4, 8), 256, 0, stream>>>(
      z1hi, z1lo, 768, 0, 768, Wh[6], Wl[6], cinp_f1, Pf1, 1024,
      z2, nullptr, nullptr, 0, 0, 512, nullptr, nullptr, 0);
  final_max_kernel<<<32, 256, 0, stream>>>(z2, out);
}

// Round 5
// 877.742 us; speedup vs baseline: 1.8493x; 1.0172x over previous
//
#include <hip/hip_runtime.h>

#define Nn 8192
#define Mm 64
#define Bb 8
#define Kk 3
#define SOMK 9
#define KN (Kk * Nn)  // 24576

__device__ __constant__ float INV_BN_C = 0.9999950000374997f;

typedef short bf16x8 __attribute__((ext_vector_type(8)));
typedef float f32x4 __attribute__((ext_vector_type(4)));

__device__ __forceinline__ unsigned short f2bf(float f) {
  unsigned int u = __float_as_uint(f);
  return (unsigned short)((u + 0x7fffu + ((u >> 16) & 1u)) >> 16);
}
__device__ __forceinline__ float bf2f(unsigned short h) {
  return __uint_as_float(((unsigned int)h) << 16);
}

// async global->LDS, 16B per lane; lds dst is wave-uniform base + lane*16
__device__ __forceinline__ void gload16(const unsigned short* g, short* l) {
  __builtin_amdgcn_global_load_lds(
      (const __attribute__((address_space(1))) unsigned int*)g,
      (__attribute__((address_space(3))) unsigned int*)l, 16, 0, 0);
}

// ---------------- SOM assignment: top-3 nearest nodes per point ----------------
__global__ __launch_bounds__(256) void som_assign_kernel(
    const float* __restrict__ x, const float* __restrict__ node,
    int* __restrict__ min_idx, float* __restrict__ counts, float* __restrict__ cl_sum) {
  int b = blockIdx.y;
  int n = blockIdx.x * 256 + threadIdx.x;
  __shared__ float nd[3][Mm];
  __shared__ float s_cnt[Mm];
  __shared__ float s_sum[Mm][3];
  int t = threadIdx.x;
  if (t < 192) nd[t / 64][t % 64] = node[(b * 3 + t / 64) * Mm + (t % 64)];
  if (t < Mm) { s_cnt[t] = 0.f; s_sum[t][0] = 0.f; s_sum[t][1] = 0.f; s_sum[t][2] = 0.f; }
  __syncthreads();
  float x0 = x[(b * 3 + 0) * Nn + n];
  float x1 = x[(b * 3 + 1) * Nn + n];
  float x2 = x[(b * 3 + 2) * Nn + n];
  float b0 = 1e30f, b1 = 1e30f, b2 = 1e30f;
  int j0 = 0, j1 = 0, j2 = 0;
  for (int m = 0; m < Mm; ++m) {
    float dx = x0 - nd[0][m];
    float dy = x1 - nd[1][m];
    float dz = x2 - nd[2][m];
    float d = __fadd_rn(__fadd_rn(__fmul_rn(dx, dx), __fmul_rn(dy, dy)), __fmul_rn(dz, dz));
    if (d < b0)      { b2 = b1; j2 = j1; b1 = b0; j1 = j0; b0 = d; j0 = m; }
    else if (d < b1) { b2 = b1; j2 = j1; b1 = d; j1 = m; }
    else if (d < b2) { b2 = d; j2 = m; }
  }
  min_idx[b * KN + 0 * Nn + n] = j0;
  min_idx[b * KN + 1 * Nn + n] = j1;
  min_idx[b * KN + 2 * Nn + n] = j2;
  atomicAdd(&s_cnt[j0], 1.f);
  atomicAdd(&s_cnt[j1], 1.f);
  atomicAdd(&s_cnt[j2], 1.f);
  atomicAdd(&s_sum[j0][0], x0); atomicAdd(&s_sum[j0][1], x1); atomicAdd(&s_sum[j0][2], x2);
  atomicAdd(&s_sum[j1][0], x0); atomicAdd(&s_sum[j1][1], x1); atomicAdd(&s_sum[j1][2], x2);
  atomicAdd(&s_sum[j2][0], x0); atomicAdd(&s_sum[j2][1], x1); atomicAdd(&s_sum[j2][2], x2);
  __syncthreads();
  if (t < Mm) {
    atomicAdd(&counts[b * Mm + t], s_cnt[t]);
    atomicAdd(&cl_sum[(b * Mm + t) * 3 + 0], s_sum[t][0]);
    atomicAdd(&cl_sum[(b * Mm + t) * 3 + 1], s_sum[t][1]);
    atomicAdd(&cl_sum[(b * Mm + t) * 3 + 2], s_sum[t][2]);
  }
}

__global__ __launch_bounds__(256) void som_node_kernel(
    const float* __restrict__ cl_sum, const float* __restrict__ counts,
    float* __restrict__ som_node) {
  int i = blockIdx.x * 256 + threadIdx.x;
  if (i >= Bb * 3 * Mm) return;
  int b = i / (3 * Mm), r = i % (3 * Mm), c = r / Mm, m = r % Mm;
  som_node[i] = cl_sum[(b * Mm + m) * 3 + c] / (counts[b * Mm + m] + 1e-5f);
}

__global__ __launch_bounds__(256) void build_h_kernel(
    const float* __restrict__ x, const float* __restrict__ sn,
    const float* __restrict__ som_node, const int* __restrict__ min_idx,
    float* __restrict__ h, int b0, int Pc) {
  int gid = blockIdx.x * 256 + threadIdx.x;
  if (gid >= 6 * Pc) return;
  int c = gid / Pc, pl = gid % Pc;
  int bl = pl / KN, i = pl % KN;
  int b = b0 + bl;
  int n = i % Nn;
  if (c < 3) {
    int idx = min_idx[b * KN + i];
    h[gid] = x[(b * 3 + c) * Nn + n] - som_node[(b * 3 + c) * Mm + idx];
  } else {
    h[gid] = sn[(b * 3 + (c - 3)) * Nn + n];
  }
}

// ---------------- weight pre-split: f32 [cout][cin] -> padded hi/lo bf16 [cout][cinp] ----------------
struct WsplitDesc {
  const float* W; unsigned short* hi; unsigned short* lo; int cin, cinp, total;
};
struct WsplitArgs { WsplitDesc d[7]; };
__global__ __launch_bounds__(256) void split_w_kernel(WsplitArgs a) {
  WsplitDesc dd = a.d[blockIdx.y];
  for (int gid = blockIdx.x * 256 + threadIdx.x; gid < dd.total; gid += gridDim.x * 256) {
    int r = gid / dd.cinp, c = gid % dd.cinp;
    float v = (c < dd.cin) ? dd.W[(size_t)r * dd.cin + c] : 0.f;
    unsigned short h = f2bf(v);
    dd.hi[gid] = h;
    dd.lo[gid] = f2bf(v - bf2f(h));
  }
}

// ---------------- f32 GEMM (cin=6) writing TRANSPOSED split-bf16 out [P][ostride] ----------------
__global__ __launch_bounds__(256) void conv_gemm_t_kernel(
    const float* __restrict__ A, const float* __restrict__ W,
    const float* __restrict__ prm, unsigned short* __restrict__ Ohi,
    unsigned short* __restrict__ Olo, int ostride, int oc0,
    int cin, int cout, int P) {
  __shared__ float Ws[16][68];
  __shared__ float As[16][64];
  int tid = threadIdx.x;
  int tx = tid % 16, ty = tid / 16;
  int p0 = blockIdx.x * 64, d0 = blockIdx.y * 64;
  float acc[4][4] = {};
  for (int k0 = 0; k0 < cin; k0 += 16) {
#pragma unroll
    for (int it = 0; it < 4; ++it) {
      int k = tid % 16, dl = tid / 16 + it * 16;
      float w = 0.f;
      if (k0 + k < cin) w = W[(size_t)(d0 + dl) * cin + k0 + k];
      Ws[k][dl] = w;
    }
#pragma unroll
    for (int it = 0; it < 4; ++it) {
      int pl = tid % 64, kl = tid / 64 + it * 4;
      float a = 0.f;
      if (k0 + kl < cin) a = A[(size_t)(k0 + kl) * P + p0 + pl];
      As[kl][pl] = a;
    }
    __syncthreads();
#pragma unroll
    for (int kk = 0; kk < 16; ++kk) {
      float4 av = *reinterpret_cast<const float4*>(&As[kk][tx * 4]);
      float4 wv = *reinterpret_cast<const float4*>(&Ws[kk][ty * 4]);
      float a4[4] = {av.x, av.y, av.z, av.w};
      float w4[4] = {wv.x, wv.y, wv.z, wv.w};
#pragma unroll
      for (int i2 = 0; i2 < 4; ++i2)
#pragma unroll
        for (int j = 0; j < 4; ++j) acc[i2][j] += w4[i2] * a4[j];
    }
    __syncthreads();
  }
#pragma unroll
  for (int i2 = 0; i2 < 4; ++i2) {
    int d = d0 + ty * 4 + i2;
    float bi = prm[d], ga = prm[cout + d], be = prm[2 * cout + d];
    float gs = ga * INV_BN_C;
#pragma unroll
    for (int j = 0; j < 4; ++j) {
      float v = (acc[i2][j] + bi) * gs + be;
      v = v > 0.f ? v : 0.f;
      size_t o = (size_t)(p0 + tx * 4 + j) * ostride + oc0 + d;
      unsigned short hh = f2bf(v);
      Ohi[o] = hh;
      Olo[o] = f2bf(v - bf2f(hh));
    }
  }
}

// ---------------- split-bf16 MFMA GEMM v2: global_load_lds + XOR-swizzled LDS ----------------
// C[d][p] = sum_k W[d][k]*A[p][k]. A transposed split-bf16 [P][astride]; W pre-split [cout][wstride].
// Tile 128x128, BK=32, 4 waves (2x2), 4x4 frags of 16x16x32.
// LDS: 4 tiles (Wh,Wl,Ah,Al) of 512 16B-slots each, swizzle g = f ^ ((f>>2)&7).
// OUT: 0 = transposed split-bf16 out; 1 = f32 [cout][P]; 2 = fused segment-max partials.
template <int OUT>
__global__ __launch_bounds__(256) void mfma3_gemm_kernel(
    const unsigned short* __restrict__ Ahi, const unsigned short* __restrict__ Alo,
    int astride, int ac0, int cin,
    const unsigned short* __restrict__ Whi, const unsigned short* __restrict__ Wlo,
    int wstride, const float* __restrict__ prm, int cout,
    float* __restrict__ outF,
    unsigned short* __restrict__ Ohi, unsigned short* __restrict__ Olo,
    int ostride, int oc0, int P,
    float* __restrict__ partial, const int* __restrict__ mi_chunk, int PBN) {
  __shared__ short smem[18432];  // 32KB tiles + epilogue scratch headroom (36.9KB)

  int tid = threadIdx.x;
  int lane = tid & 63, wave = tid >> 6;
  int wm = wave >> 1, wn = wave & 1;
  int lane15 = lane & 15, lh = lane >> 4;
  int p0 = blockIdx.x * 128, d0 = blockIdx.y * 128;

  // ---- staging: inverse swizzle f(g): f0=g0^g2^g4, f1=g1^g3, f2=g2^g4 ----
  int f0 = (lane ^ (lane >> 2) ^ (lane >> 4)) & 1;
  int f1 = ((lane >> 1) ^ (lane >> 3)) & 1;
  int f2 = ((lane >> 2) ^ (lane >> 4)) & 1;
  int fl = (lane & 56) | (f2 << 2) | (f1 << 1) | f0;  // 0..63
  int rl = fl >> 2, sl = fl & 3;                      // row-in-16, 16B slot-in-row

  const unsigned short *pWh[2], *pWl[2], *pAh[2], *pAl[2];
  short *dWh[2], *dWl[2], *dAh[2], *dAl[2];
#pragma unroll
  for (int c = 0; c < 2; ++c) {
    int gr = wave * 32 + c * 16 + rl;  // row within 128-row tile
    size_t wb = (size_t)(d0 + gr) * wstride + sl * 8;
    size_t ab = (size_t)(p0 + gr) * astride + ac0 + sl * 8;
    pWh[c] = Whi + wb; pWl[c] = Wlo + wb;
    pAh[c] = Ahi + ab; pAl[c] = Alo + ab;
    int sb = (wave * 128 + c * 64) * 8;  // short offset of this wave's 64-slot chunk
    dWh[c] = smem + 0 * 4096 + sb;
    dWl[c] = smem + 1 * 4096 + sb;
    dAh[c] = smem + 2 * 4096 + sb;
    dAl[c] = smem + 3 * 4096 + sb;
  }

  // ---- swizzled ds_read offsets (shorts) for hi tiles; lo = +4096 ----
  int offW[4], offA[4];
#pragma unroll
  for (int i = 0; i < 4; ++i) {
    int rowW = wm * 64 + i * 16 + lane15;
    offW[i] = (((rowW * 4 + lh) ^ (lane & 7))) * 8;
    int rowA = wn * 64 + i * 16 + lane15;
    offA[i] = (((rowA * 4 + lh) ^ (lane & 7))) * 8;
  }

  f32x4 acc[4][4] = {};

  for (int k0 = 0; k0 < cin; k0 += 32) {
#pragma unroll
    for (int c = 0; c < 2; ++c) {
      gload16(pWh[c], dWh[c]); pWh[c] += 32;
      gload16(pWl[c], dWl[c]); pWl[c] += 32;
      gload16(pAh[c], dAh[c]); pAh[c] += 32;
      gload16(pAl[c], dAl[c]); pAl[c] += 32;
    }
    __syncthreads();  // compiler drains vmcnt before s_barrier
    bf16x8 wa_h[4], wa_l[4], xb_h[4], xb_l[4];
#pragma unroll
    for (int i = 0; i < 4; ++i) {
      wa_h[i] = *reinterpret_cast<const bf16x8*>(&smem[offW[i]]);
      wa_l[i] = *reinterpret_cast<const bf16x8*>(&smem[4096 + offW[i]]);
      xb_h[i] = *reinterpret_cast<const bf16x8*>(&smem[8192 + offA[i]]);
      xb_l[i] = *reinterpret_cast<const bf16x8*>(&smem[12288 + offA[i]]);
    }
#pragma unroll
    for (int mi = 0; mi < 4; ++mi)
#pragma unroll
      for (int ni = 0; ni < 4; ++ni) {
        acc[mi][ni] = __builtin_amdgcn_mfma_f32_16x16x32_bf16(wa_h[mi], xb_h[ni], acc[mi][ni], 0, 0, 0);
        acc[mi][ni] = __builtin_amdgcn_mfma_f32_16x16x32_bf16(wa_h[mi], xb_l[ni], acc[mi][ni], 0, 0, 0);
        acc[mi][ni] = __builtin_amdgcn_mfma_f32_16x16x32_bf16(wa_l[mi], xb_h[ni], acc[mi][ni], 0, 0, 0);
      }
    __syncthreads();
  }

  if (OUT == 2) {
    // fused segment-max: LDS-reduce tile over p grouped by cluster m, write partials
    float* s_nf = (float*)smem;              // [64 m][132] padded = 33792 B
    int* s_mi = (int*)(smem + 16896);        // [128]
    for (int i = tid; i < 64 * 132; i += 256) s_nf[i] = 0.f;
    if (tid < 128) s_mi[tid] = mi_chunk[p0 + tid];
    __syncthreads();
    int mloc[4];
#pragma unroll
    for (int ni = 0; ni < 4; ++ni) mloc[ni] = s_mi[wn * 64 + ni * 16 + lane15];
#pragma unroll
    for (int mi = 0; mi < 4; ++mi) {
      int dbase = wm * 64 + mi * 16 + lh * 4;
#pragma unroll
      for (int ni = 0; ni < 4; ++ni) {
        int m = mloc[ni];
#pragma unroll
        for (int r = 0; r < 4; ++r) {
          int d = d0 + dbase + r;
          float bi = prm[d], ga = prm[cout + d], be = prm[2 * cout + d];
          float v = (acc[mi][ni][r] + bi) * (ga * INV_BN_C) + be;
          if (v > 0.f)
            atomicMax((unsigned*)&s_nf[m * 132 + dbase + r], __float_as_uint(v));
        }
      }
    }
    __syncthreads();
    float* pout = partial + ((size_t)(blockIdx.y * PBN + blockIdx.x) * 64) * 128;
    for (int i = tid; i < 8192; i += 256) {
      int m = i >> 7, dl = i & 127;
      pout[i] = s_nf[m * 132 + dl];
    }
    return;
  }

#pragma unroll
  for (int mi = 0; mi < 4; ++mi) {
    int dbase = d0 + wm * 64 + mi * 16 + lh * 4;
#pragma unroll
    for (int ni = 0; ni < 4; ++ni) {
      int p = p0 + wn * 64 + ni * 16 + lane15;
      float vv[4];
#pragma unroll
      for (int r = 0; r < 4; ++r) {
        int d = dbase + r;
        float bi = prm[d], ga = prm[cout + d], be = prm[2 * cout + d];
        float v = (acc[mi][ni][r] + bi) * (ga * INV_BN_C) + be;
        vv[r] = v > 0.f ? v : 0.f;
      }
      if (OUT == 1) {
#pragma unroll
        for (int r = 0; r < 4; ++r) outF[(size_t)(dbase + r) * P + p] = vv[r];
      } else {
        ushort4 hh, ll;
        hh.x = f2bf(vv[0]); ll.x = f2bf(vv[0] - bf2f(hh.x));
        hh.y = f2bf(vv[1]); ll.y = f2bf(vv[1] - bf2f(hh.y));
        hh.z = f2bf(vv[2]); ll.z = f2bf(vv[2] - bf2f(hh.z));
        hh.w = f2bf(vv[3]); ll.w = f2bf(vv[3] - bf2f(hh.w));
        size_t o = (size_t)p * ostride + oc0 + dbase;
        *reinterpret_cast<ushort4*>(&Ohi[o]) = hh;
        *reinterpret_cast<ushort4*>(&Olo[o]) = ll;
      }
    }
  }
}

// ---------------- reduce partials -> node_feat [B*M][384] ----------------
__global__ __launch_bounds__(256) void reduce_nf_kernel(
    const float* __restrict__ part, float* __restrict__ nf, int PBN, int b0, int Bc) {
  int gid = blockIdx.x * 256 + threadIdx.x;  // over 3*Bc*64*128
  int yblk = gid / (Bc * 8192);
  int rem = gid % (Bc * 8192);
  int bl = rem / 8192, r = rem % 8192;
  int m = r >> 7, dl = r & 127;
  float v = 0.f;
  const float* src = part + ((size_t)(yblk * PBN + bl * 192) * 64 + m) * 128 + dl;
  for (int j = 0; j < 192; ++j) v = fmaxf(v, src[(size_t)j * 8192]);
  nf[((size_t)((b0 + bl) * Mm + m)) * 384 + yblk * 128 + dl] = v;
}

// ---------------- build g transposed split-bf16 [4608][416]; also centerb ----------------
__global__ __launch_bounds__(256) void build_g_t_kernel(
    const float* __restrict__ som_node, const float* __restrict__ node_feat,
    const int* __restrict__ knnI, unsigned short* __restrict__ ghi,
    unsigned short* __restrict__ glo, float* __restrict__ centerb) {
  int p = blockIdx.x;  // b*576 + m*9 + s
  int b = p / (Mm * SOMK), r = p % (Mm * SOMK), m = r / SOMK, s = r % SOMK;
  int t = threadIdx.x;
  __shared__ int nb[SOMK];
  __shared__ float ctr[3];
  if (t < SOMK) nb[t] = knnI[(b * Mm + m) * SOMK + t];
  __syncthreads();
  if (t < 3) {
    float sum = 0.f;
    for (int ss = 0; ss < SOMK; ++ss) sum += som_node[(b * 3 + t) * Mm + nb[ss]];
    float c = sum / 9.f;
    ctr[t] = c;
    if (s == 0) centerb[(b * 3 + t) * Mm + m] = c;
  }
  __syncthreads();
  int idx = nb[s];
  for (int c = t; c < 416; c += 256) {
    float v;
    if (c < 3) v = som_node[(b * 3 + c) * Mm + idx] - ctr[c];
    else if (c < 387) v = node_feat[((size_t)(b * Mm + idx)) * 384 + (c - 3)];
    else v = 0.f;
    unsigned short hh = f2bf(v);
    size_t o = (size_t)p * 416 + c;
    ghi[o] = hh;
    glo[o] = f2bf(v - bf2f(hh));
  }
}

// ---------------- build z transposed split-bf16 [512][544] from g3 f32 [512][4608] ----------------
__global__ __launch_bounds__(256) void build_z_t_kernel(
    const float* __restrict__ centerb, const float* __restrict__ g3,
    unsigned short* __restrict__ zhi, unsigned short* __restrict__ zlo) {
  int p = blockIdx.x;  // b*64 + m
  int b = p >> 6, m = p & 63;
  int t = threadIdx.x;
  for (int c = t; c < 544; c += 256) {
    float v;
    if (c < 3) {
      v = centerb[(b * 3 + c) * Mm + m];
    } else if (c < 515) {
      const float* src = g3 + (size_t)(c - 3) * (Bb * Mm * SOMK) + b * (Mm * SOMK) + m * SOMK;
      v = src[0];
      for (int s = 1; s < SOMK; ++s) v = fmaxf(v, src[s]);
    } else {
      v = 0.f;
    }
    unsigned short hh = f2bf(v);
    size_t o = (size_t)p * 544 + c;
    zhi[o] = hh;
    zlo[o] = f2bf(v - bf2f(hh));
  }
}

__global__ __launch_bounds__(256) void final_max_kernel(
    const float* __restrict__ z2, float* __restrict__ out) {
  int gid = blockIdx.x * 256 + threadIdx.x;
  if (gid >= Bb * 1024) return;
  int b = gid / 1024, d = gid % 1024;
  const float* src = z2 + (size_t)d * (Bb * Mm) + b * Mm;
  float v = src[0];
  for (int m = 1; m < Mm; ++m) v = fmaxf(v, src[m]);
  out[gid] = v;
}

extern "C" void kernel_launch(void* const* d_in, const int* in_sizes, int n_in,
                              void* d_out, int out_size, void* d_ws, size_t ws_size,
                              hipStream_t stream) {
  (void)in_sizes; (void)n_in; (void)out_size;
  const float* x = (const float*)d_in[0];
  const float* sn = (const float*)d_in[1];
  const float* node = (const float*)d_in[2];
  const int* knnI = (const int*)d_in[3];
  const float* Wfp0 = (const float*)d_in[4];  const float* Pfp0 = (const float*)d_in[5];
  const float* Wfp1 = (const float*)d_in[6];  const float* Pfp1 = (const float*)d_in[7];
  const float* Wfp2 = (const float*)d_in[8];  const float* Pfp2 = (const float*)d_in[9];
  const float* Wfp3 = (const float*)d_in[10]; const float* Pfp3 = (const float*)d_in[11];
  const float* Wk0  = (const float*)d_in[12]; const float* Pk0  = (const float*)d_in[13];
  const float* Wk1  = (const float*)d_in[14]; const float* Pk1  = (const float*)d_in[15];
  const float* Wf0  = (const float*)d_in[16]; const float* Pf0  = (const float*)d_in[17];
  const float* Wf1  = (const float*)d_in[18]; const float* Pf1  = (const float*)d_in[19];
  float* out = (float*)d_out;

  char* ws = (char*)d_ws;
  size_t off = 0;
  auto alloc = [&](size_t bytes) -> void* {
    void* p = ws + off;
    off += (bytes + 255) & ~(size_t)255;
    return p;
  };
  float* counts    = (float*)alloc(512 * 4);
  float* cl_sum    = (float*)alloc(1536 * 4);
  float* som_node  = (float*)alloc(1536 * 4);
  float* centerb   = (float*)alloc(1536 * 4);
  int*   min_idx   = (int*)alloc((size_t)Bb * KN * 4);
  float* node_feat = (float*)alloc((size_t)Bb * Mm * 384 * 4);

  // pre-split weight buffers (hi/lo, padded cin)
  const int cinp_fp1 = 64, cinp_fp2 = 128, cinp_fp3 = 320;
  const int cinp_k0 = 416, cinp_k1 = 512, cinp_f0 = 544, cinp_f1 = 768;
  unsigned short *Wh[7], *Wl[7];
  int wtot[7] = {128 * 64, 256 * 128, 384 * 320, 512 * 416, 512 * 512, 768 * 544, 1024 * 768};
  for (int i = 0; i < 7; ++i) {
    Wh[i] = (unsigned short*)alloc((size_t)wtot[i] * 2);
    Wl[i] = (unsigned short*)alloc((size_t)wtot[i] * 2);
  }

  unsigned short* ghi  = (unsigned short*)alloc(4608ull * 416 * 2);
  unsigned short* glo  = (unsigned short*)alloc(4608ull * 416 * 2);
  unsigned short* g2hi = (unsigned short*)alloc(4608ull * 512 * 2);
  unsigned short* g2lo = (unsigned short*)alloc(4608ull * 512 * 2);
  float* g3 = (float*)alloc(512ull * 4608 * 4);
  unsigned short* zbhi = (unsigned short*)alloc(512ull * 544 * 2);
  unsigned short* zblo = (unsigned short*)alloc(512ull * 544 * 2);
  unsigned short* z1hi = (unsigned short*)alloc(512ull * 768 * 2);
  unsigned short* z1lo = (unsigned short*)alloc(512ull * 768 * 2);
  float* z2 = (float*)alloc(1024ull * 512 * 4);
  size_t small_end = off;

  // per-chunk: h 24 B/pt + A1 hi/lo 1280 + y1 hi/lo 512 + partial 768 = 2584 B/pt
  size_t per_b = 2584ull * KN;
  int Bc = 1;
  if (small_end + 8 * per_b + 4096 <= ws_size) Bc = 8;
  else if (small_end + 4 * per_b + 4096 <= ws_size) Bc = 4;
  else if (small_end + 2 * per_b + 4096 <= ws_size) Bc = 2;
  int Pc = Bc * KN;
  int PBN = Pc / 128;
  float* h = (float*)alloc(6ull * Pc * 4);
  unsigned short* A1hi = (unsigned short*)alloc(320ull * Pc * 2);
  unsigned short* A1lo = (unsigned short*)alloc(320ull * Pc * 2);
  unsigned short* y1hi = (unsigned short*)alloc(128ull * Pc * 2);
  unsigned short* y1lo = (unsigned short*)alloc(128ull * Pc * 2);
  float* Ppart = (float*)alloc(3ull * PBN * 64 * 128 * 4);

  hipMemsetAsync(counts, 0, 512 * 4, stream);
  hipMemsetAsync(cl_sum, 0, 1536 * 4, stream);
  som_assign_kernel<<<dim3(Nn / 256, Bb), 256, 0, stream>>>(x, node, min_idx, counts, cl_sum);
  som_node_kernel<<<6, 256, 0, stream>>>(cl_sum, counts, som_node);

  {
    WsplitArgs wa;
    const float* Wsrc[7] = {Wfp1, Wfp2, Wfp3, Wk0, Wk1, Wf0, Wf1};
    int cins[7] = {64, 128, 320, 387, 512, 515, 768};
    int cinps[7] = {cinp_fp1, cinp_fp2, cinp_fp3, cinp_k0, cinp_k1, cinp_f0, cinp_f1};
    for (int i = 0; i < 7; ++i)
      wa.d[i] = WsplitDesc{Wsrc[i], Wh[i], Wl[i], cins[i], cinps[i], wtot[i]};
    split_w_kernel<<<dim3(128, 7), 256, 0, stream>>>(wa);
  }

  for (int b0 = 0; b0 < Bb; b0 += Bc) {
    build_h_kernel<<<(6 * Pc) / 256, 256, 0, stream>>>(x, sn, som_node, min_idx, h, b0, Pc);
    // fp0: f32 GEMM (cin=6) -> transposed split-bf16 into A1 cols 0..63
    conv_gemm_t_kernel<<<dim3(Pc / 64, 1), 256, 0, stream>>>(
        h, Wfp0, Pfp0, A1hi, A1lo, 320, 0, 6, 64, Pc);
    // fp1: 64 -> 128
    mfma3_gemm_kernel<0><<<dim3(Pc / 128, 1), 256, 0, stream>>>(
        A1hi, A1lo, 320, 0, 64, Wh[0], Wl[0], cinp_fp1, Pfp1, 128,
        nullptr, y1hi, y1lo, 128, 0, Pc, nullptr, nullptr, 0);
    // fp2: 128 -> 256 into A1 cols 64..319
    mfma3_gemm_kernel<0><<<dim3(Pc / 128, 2), 256, 0, stream>>>(
        y1hi, y1lo, 128, 0, 128, Wh[1], Wl[1], cinp_fp2, Pfp2, 256,
        nullptr, A1hi, A1lo, 320, 64, Pc, nullptr, nullptr, 0);
    // fp3: 320 -> 384, fused segment-max partials
    mfma3_gemm_kernel<2><<<dim3(PBN, 3), 256, 0, stream>>>(
        A1hi, A1lo, 320, 0, 320, Wh[2], Wl[2], cinp_fp3, Pfp3, 384,
        nullptr, nullptr, nullptr, 0, 0, Pc, Ppart, min_idx + b0 * KN, PBN);
    reduce_nf_kernel<<<96 * Bc, 256, 0, stream>>>(Ppart, node_feat, PBN, b0, Bc);
  }

  build_g_t_kernel<<<4608, 256, 0, stream>>>(som_node, node_feat, knnI, ghi, glo, centerb);
  // knn0: 416 -> 512
  mfma3_gemm_kernel<0><<<dim3(36, 4), 256, 0, stream>>>(
      ghi, glo, 416, 0, 416, Wh[3], Wl[3], cinp_k0, Pk0, 512,
      nullptr, g2hi, g2lo, 512, 0, 4608, nullptr, nullptr, 0);
  // knn1: 512 -> 512, f32 out g3
  mfma3_gemm_kernel<1><<<dim3(36, 4), 256, 0, stream>>>(
      g2hi, g2lo, 512, 0, 512, Wh[4], Wl[4], cinp_k1, Pk1, 512,
      g3, nullptr, nullptr, 0, 0, 4608, nullptr, nullptr, 0);
  build_z_t_kernel<<<512, 256, 0, stream>>>(centerb, g3, zbhi, zblo);
  // fin0: 544 -> 768
  mfma3_gemm_kernel<0><<<dim3(4, 6), 256, 0, stream>>>(
      zbhi, zblo, 544, 0, 544, Wh[5], Wl[5], cinp_f0, Pf0, 768,
      nullptr, z1hi, z1lo, 768, 0, 512, nullptr, nullptr, 0);
  // fin1: 768 -> 1024, f32 out z2
  mfma3_gemm_kernel<1><<<dim3(4, 8), 256, 0, stream>>>(
      z1hi, z1lo, 768, 0, 768, Wh[6], Wl[6], cinp_f1, Pf1, 1024,
      z2, nullptr, nullptr, 0, 0, 512, nullptr, nullptr, 0);
  final_max_kernel<<<32, 256, 0, stream>>>(z2, out);
}

// Round 6
// 582.319 us; speedup vs baseline: 2.7874x; 1.5073x over previous
//
#include <hip/hip_runtime.h>

#define Nn 8192
#define Mm 64
#define Bb 8
#define Kk 3
#define SOMK 9
#define KN (Kk * Nn)  // 24576

__device__ __constant__ float INV_BN_C = 0.9999950000374997f;

typedef short bf16x8 __attribute__((ext_vector_type(8)));
typedef float f32x4 __attribute__((ext_vector_type(4)));

__device__ __forceinline__ unsigned short f2bf(float f) {
  unsigned int u = __float_as_uint(f);
  return (unsigned short)((u + 0x7fffu + ((u >> 16) & 1u)) >> 16);
}
__device__ __forceinline__ float bf2f(unsigned short h) {
  return __uint_as_float(((unsigned int)h) << 16);
}

// async global->LDS, 16B per lane; lds dst is wave-uniform base + lane*16
__device__ __forceinline__ void gload16(const unsigned short* g, short* l) {
  __builtin_amdgcn_global_load_lds(
      (const __attribute__((address_space(1))) unsigned int*)g,
      (__attribute__((address_space(3))) unsigned int*)l, 16, 0, 0);
}

// ---------------- SOM assignment: top-3 nearest nodes per point ----------------
__global__ __launch_bounds__(256) void som_assign_kernel(
    const float* __restrict__ x, const float* __restrict__ node,
    int* __restrict__ min_idx, float* __restrict__ counts, float* __restrict__ cl_sum) {
  int b = blockIdx.y;
  int n = blockIdx.x * 256 + threadIdx.x;
  __shared__ float nd[3][Mm];
  __shared__ float s_cnt[Mm];
  __shared__ float s_sum[Mm][3];
  int t = threadIdx.x;
  if (t < 192) nd[t / 64][t % 64] = node[(b * 3 + t / 64) * Mm + (t % 64)];
  if (t < Mm) { s_cnt[t] = 0.f; s_sum[t][0] = 0.f; s_sum[t][1] = 0.f; s_sum[t][2] = 0.f; }
  __syncthreads();
  float x0 = x[(b * 3 + 0) * Nn + n];
  float x1 = x[(b * 3 + 1) * Nn + n];
  float x2 = x[(b * 3 + 2) * Nn + n];
  float b0 = 1e30f, b1 = 1e30f, b2 = 1e30f;
  int j0 = 0, j1 = 0, j2 = 0;
  for (int m = 0; m < Mm; ++m) {
    float dx = x0 - nd[0][m];
    float dy = x1 - nd[1][m];
    float dz = x2 - nd[2][m];
    float d = __fadd_rn(__fadd_rn(__fmul_rn(dx, dx), __fmul_rn(dy, dy)), __fmul_rn(dz, dz));
    if (d < b0)      { b2 = b1; j2 = j1; b1 = b0; j1 = j0; b0 = d; j0 = m; }
    else if (d < b1) { b2 = b1; j2 = j1; b1 = d; j1 = m; }
    else if (d < b2) { b2 = d; j2 = m; }
  }
  min_idx[b * KN + 0 * Nn + n] = j0;
  min_idx[b * KN + 1 * Nn + n] = j1;
  min_idx[b * KN + 2 * Nn + n] = j2;
  atomicAdd(&s_cnt[j0], 1.f);
  atomicAdd(&s_cnt[j1], 1.f);
  atomicAdd(&s_cnt[j2], 1.f);
  atomicAdd(&s_sum[j0][0], x0); atomicAdd(&s_sum[j0][1], x1); atomicAdd(&s_sum[j0][2], x2);
  atomicAdd(&s_sum[j1][0], x0); atomicAdd(&s_sum[j1][1], x1); atomicAdd(&s_sum[j1][2], x2);
  atomicAdd(&s_sum[j2][0], x0); atomicAdd(&s_sum[j2][1], x1); atomicAdd(&s_sum[j2][2], x2);
  __syncthreads();
  if (t < Mm) {
    atomicAdd(&counts[b * Mm + t], s_cnt[t]);
    atomicAdd(&cl_sum[(b * Mm + t) * 3 + 0], s_sum[t][0]);
    atomicAdd(&cl_sum[(b * Mm + t) * 3 + 1], s_sum[t][1]);
    atomicAdd(&cl_sum[(b * Mm + t) * 3 + 2], s_sum[t][2]);
  }
}

__global__ __launch_bounds__(256) void som_node_kernel(
    const float* __restrict__ cl_sum, const float* __restrict__ counts,
    float* __restrict__ som_node) {
  int i = blockIdx.x * 256 + threadIdx.x;
  if (i >= Bb * 3 * Mm) return;
  int b = i / (3 * Mm), r = i % (3 * Mm), c = r / Mm, m = r % Mm;
  som_node[i] = cl_sum[(b * Mm + m) * 3 + c] / (counts[b * Mm + m] + 1e-5f);
}

// ---------------- weight pre-split: f32 [cout][cin] -> padded hi/lo bf16 [cout][cinp] ----------------
struct WsplitDesc {
  const float* W; unsigned short* hi; unsigned short* lo; int cin, cinp, total;
};
struct WsplitArgs { WsplitDesc d[7]; };
__global__ __launch_bounds__(256) void split_w_kernel(WsplitArgs a) {
  WsplitDesc dd = a.d[blockIdx.y];
  for (int gid = blockIdx.x * 256 + threadIdx.x; gid < dd.total; gid += gridDim.x * 256) {
    int r = gid / dd.cinp, c = gid % dd.cinp;
    float v = (c < dd.cin) ? dd.W[(size_t)r * dd.cin + c] : 0.f;
    unsigned short h = f2bf(v);
    dd.hi[gid] = h;
    dd.lo[gid] = f2bf(v - bf2f(h));
  }
}

// ---------------- fp0: fused build_h + f32 GEMM (cin=6) -> transposed bf16 [P][ostride] ----------------
__global__ __launch_bounds__(256) void conv_gemm_t_kernel(
    const float* __restrict__ x, const float* __restrict__ sn,
    const float* __restrict__ som_node, const int* __restrict__ min_idx, int b0,
    const float* __restrict__ W, const float* __restrict__ prm,
    unsigned short* __restrict__ Ohi, int ostride, int oc0,
    int cin, int cout, int P) {
  __shared__ float Ws[16][68];
  __shared__ float As[16][64];
  int tid = threadIdx.x;
  int tx = tid % 16, ty = tid / 16;
  int p0 = blockIdx.x * 64, d0 = blockIdx.y * 64;
  float acc[4][4] = {};
  {
#pragma unroll
    for (int it = 0; it < 4; ++it) {
      int k = tid % 16, dl = tid / 16 + it * 16;
      float w = 0.f;
      if (k < cin) w = W[(size_t)(d0 + dl) * cin + k];
      Ws[k][dl] = w;
    }
#pragma unroll
    for (int it = 0; it < 4; ++it) {
      int pl = tid % 64, kl = tid / 64 + it * 4;
      int p = p0 + pl;
      int bl = p / KN, i = p % KN;
      int b = b0 + bl;
      int n = i % Nn;
      float a = 0.f;
      if (kl < 3) {
        int idx = min_idx[b * KN + i];
        a = x[(b * 3 + kl) * Nn + n] - som_node[(b * 3 + kl) * Mm + idx];
      } else if (kl < 6) {
        a = sn[(b * 3 + (kl - 3)) * Nn + n];
      }
      As[kl][pl] = a;
    }
    __syncthreads();
#pragma unroll
    for (int kk = 0; kk < 16; ++kk) {
      float4 av = *reinterpret_cast<const float4*>(&As[kk][tx * 4]);
      float4 wv = *reinterpret_cast<const float4*>(&Ws[kk][ty * 4]);
      float a4[4] = {av.x, av.y, av.z, av.w};
      float w4[4] = {wv.x, wv.y, wv.z, wv.w};
#pragma unroll
      for (int i2 = 0; i2 < 4; ++i2)
#pragma unroll
        for (int j = 0; j < 4; ++j) acc[i2][j] += w4[i2] * a4[j];
    }
  }
#pragma unroll
  for (int i2 = 0; i2 < 4; ++i2) {
    int d = d0 + ty * 4 + i2;
    float bi = prm[d], ga = prm[cout + d], be = prm[2 * cout + d];
    float gs = ga * INV_BN_C;
#pragma unroll
    for (int j = 0; j < 4; ++j) {
      float v = (acc[i2][j] + bi) * gs + be;
      v = v > 0.f ? v : 0.f;
      Ohi[(size_t)(p0 + tx * 4 + j) * ostride + oc0 + d] = f2bf(v);
    }
  }
}

// ---------------- W-split MFMA GEMM: act bf16, W hi/lo (2 MFMAs per unit) ----------------
// C[d][p] = sum_k W[d][k]*A[p][k]. A transposed bf16 [P][astride]; W pre-split [cout][wstride].
// Tile 128x128, BK=32, 4 waves (2x2), 4x4 frags of 16x16x32. global_load_lds + XOR swizzle.
// OUT: 0 = transposed bf16 out; 1 = f32 [cout][P]; 2 = fused segment-max via global atomicMax.
template <int OUT>
__global__ __launch_bounds__(256) void mfma3_gemm_kernel(
    const unsigned short* __restrict__ Ahi, int astride, int ac0, int cin,
    const unsigned short* __restrict__ Whi, const unsigned short* __restrict__ Wlo,
    int wstride, const float* __restrict__ prm, int cout,
    float* __restrict__ outF,
    unsigned short* __restrict__ Ohi, int ostride, int oc0, int P,
    unsigned* __restrict__ nf, const int* __restrict__ mi_chunk, int b0) {
  __shared__ short smem[16384];  // 32 KB: 3 tiles (24KB) in loop; s_nf (32KB) in epilogue

  int tid = threadIdx.x;
  int lane = tid & 63, wave = tid >> 6;
  int wm = wave >> 1, wn = wave & 1;
  int lane15 = lane & 15, lh = lane >> 4;
  int p0 = blockIdx.x * 128, d0 = blockIdx.y * 128;

  // ---- staging: inverse swizzle f(g): f0=g0^g2^g4, f1=g1^g3, f2=g2^g4 ----
  int f0 = (lane ^ (lane >> 2) ^ (lane >> 4)) & 1;
  int f1 = ((lane >> 1) ^ (lane >> 3)) & 1;
  int f2 = ((lane >> 2) ^ (lane >> 4)) & 1;
  int fl = (lane & 56) | (f2 << 2) | (f1 << 1) | f0;  // 0..63
  int rl = fl >> 2, sl = fl & 3;                      // row-in-16, 16B slot-in-row

  const unsigned short *pWh[2], *pWl[2], *pA[2];
  short *dWh[2], *dWl[2], *dA[2];
#pragma unroll
  for (int c = 0; c < 2; ++c) {
    int gr = wave * 32 + c * 16 + rl;  // row within 128-row tile
    size_t wb = (size_t)(d0 + gr) * wstride + sl * 8;
    size_t ab = (size_t)(p0 + gr) * astride + ac0 + sl * 8;
    pWh[c] = Whi + wb; pWl[c] = Wlo + wb;
    pA[c] = Ahi + ab;
    int sb = (wave * 128 + c * 64) * 8;  // short offset of this wave's 64-slot chunk
    dWh[c] = smem + 0 * 4096 + sb;
    dWl[c] = smem + 1 * 4096 + sb;
    dA[c]  = smem + 2 * 4096 + sb;
  }

  // ---- swizzled ds_read offsets (shorts) ----
  int offW[4], offA[4];
#pragma unroll
  for (int i = 0; i < 4; ++i) {
    int rowW = wm * 64 + i * 16 + lane15;
    offW[i] = (((rowW * 4 + lh) ^ (lane & 7))) * 8;
    int rowA = wn * 64 + i * 16 + lane15;
    offA[i] = (((rowA * 4 + lh) ^ (lane & 7))) * 8;
  }

  f32x4 acc[4][4] = {};

  for (int k0 = 0; k0 < cin; k0 += 32) {
#pragma unroll
    for (int c = 0; c < 2; ++c) {
      gload16(pWh[c], dWh[c]); pWh[c] += 32;
      gload16(pWl[c], dWl[c]); pWl[c] += 32;
      gload16(pA[c],  dA[c]);  pA[c]  += 32;
    }
    __syncthreads();  // compiler drains vmcnt before s_barrier
    bf16x8 wa_h[4], wa_l[4], xb[4];
#pragma unroll
    for (int i = 0; i < 4; ++i) {
      wa_h[i] = *reinterpret_cast<const bf16x8*>(&smem[offW[i]]);
      wa_l[i] = *reinterpret_cast<const bf16x8*>(&smem[4096 + offW[i]]);
      xb[i]   = *reinterpret_cast<const bf16x8*>(&smem[8192 + offA[i]]);
    }
#pragma unroll
    for (int mi = 0; mi < 4; ++mi)
#pragma unroll
      for (int ni = 0; ni < 4; ++ni) {
        acc[mi][ni] = __builtin_amdgcn_mfma_f32_16x16x32_bf16(wa_h[mi], xb[ni], acc[mi][ni], 0, 0, 0);
        acc[mi][ni] = __builtin_amdgcn_mfma_f32_16x16x32_bf16(wa_l[mi], xb[ni], acc[mi][ni], 0, 0, 0);
      }
    __syncthreads();
  }

  if (OUT == 2) {
    // fused segment-max: LDS-reduce tile over p grouped by cluster m (XOR-swizzled banks),
    // then one global atomicMax per (m,d) into node_feat (memset to 0 by host).
    float* s_nf = (float*)smem;  // [64][128] with idx = m*128 + (d ^ m)
    for (int i = tid; i < 8192; i += 256) s_nf[i] = 0.f;
    int mloc[4];
#pragma unroll
    for (int ni = 0; ni < 4; ++ni) mloc[ni] = mi_chunk[p0 + wn * 64 + ni * 16 + lane15];
    __syncthreads();
#pragma unroll
    for (int mi = 0; mi < 4; ++mi) {
      int dbase = wm * 64 + mi * 16 + lh * 4;
#pragma unroll
      for (int ni = 0; ni < 4; ++ni) {
        int m = mloc[ni];
#pragma unroll
        for (int r = 0; r < 4; ++r) {
          int d = d0 + dbase + r;
          float bi = prm[d], ga = prm[cout + d], be = prm[2 * cout + d];
          float v = (acc[mi][ni][r] + bi) * (ga * INV_BN_C) + be;
          if (v > 0.f)
            atomicMax((unsigned*)&s_nf[m * 128 + ((dbase + r) ^ m)], __float_as_uint(v));
        }
      }
    }
    __syncthreads();
    int bl = p0 / KN;  // all 128 points of this block share one batch element
    size_t nfbase = ((size_t)((b0 + bl) * Mm)) * 384 + blockIdx.y * 128;
    for (int i = tid; i < 8192; i += 256) {
      int m = i >> 7, dl = i & 127;
      float v = s_nf[m * 128 + (dl ^ m)];
      if (v > 0.f) atomicMax(&nf[nfbase + (size_t)m * 384 + dl], __float_as_uint(v));
    }
    return;
  }

#pragma unroll
  for (int mi = 0; mi < 4; ++mi) {
    int dbase = d0 + wm * 64 + mi * 16 + lh * 4;
#pragma unroll
    for (int ni = 0; ni < 4; ++ni) {
      int p = p0 + wn * 64 + ni * 16 + lane15;
      float vv[4];
#pragma unroll
      for (int r = 0; r < 4; ++r) {
        int d = dbase + r;
        float bi = prm[d], ga = prm[cout + d], be = prm[2 * cout + d];
        float v = (acc[mi][ni][r] + bi) * (ga * INV_BN_C) + be;
        vv[r] = v > 0.f ? v : 0.f;
      }
      if (OUT == 1) {
#pragma unroll
        for (int r = 0; r < 4; ++r) outF[(size_t)(dbase + r) * P + p] = vv[r];
      } else {
        ushort4 hh;
        hh.x = f2bf(vv[0]); hh.y = f2bf(vv[1]); hh.z = f2bf(vv[2]); hh.w = f2bf(vv[3]);
        *reinterpret_cast<ushort4*>(&Ohi[(size_t)p * ostride + oc0 + dbase]) = hh;
      }
    }
  }
}

// ---------------- build g transposed bf16 [4608][416]; also centerb ----------------
__global__ __launch_bounds__(256) void build_g_t_kernel(
    const float* __restrict__ som_node, const float* __restrict__ node_feat,
    const int* __restrict__ knnI, unsigned short* __restrict__ ghi,
    float* __restrict__ centerb) {
  int p = blockIdx.x;  // b*576 + m*9 + s
  int b = p / (Mm * SOMK), r = p % (Mm * SOMK), m = r / SOMK, s = r % SOMK;
  int t = threadIdx.x;
  __shared__ int nb[SOMK];
  __shared__ float ctr[3];
  if (t < SOMK) nb[t] = knnI[(b * Mm + m) * SOMK + t];
  __syncthreads();
  if (t < 3) {
    float sum = 0.f;
    for (int ss = 0; ss < SOMK; ++ss) sum += som_node[(b * 3 + t) * Mm + nb[ss]];
    float c = sum / 9.f;
    ctr[t] = c;
    if (s == 0) centerb[(b * 3 + t) * Mm + m] = c;
  }
  __syncthreads();
  int idx = nb[s];
  for (int c = t; c < 416; c += 256) {
    float v;
    if (c < 3) v = som_node[(b * 3 + c) * Mm + idx] - ctr[c];
    else if (c < 387) v = node_feat[((size_t)(b * Mm + idx)) * 384 + (c - 3)];
    else v = 0.f;
    ghi[(size_t)p * 416 + c] = f2bf(v);
  }
}

// ---------------- build z transposed bf16 [512][544] from g3 f32 [512][4608] ----------------
__global__ __launch_bounds__(256) void build_z_t_kernel(
    const float* __restrict__ centerb, const float* __restrict__ g3,
    unsigned short* __restrict__ zhi) {
  int p = blockIdx.x;  // b*64 + m
  int b = p >> 6, m = p & 63;
  int t = threadIdx.x;
  for (int c = t; c < 544; c += 256) {
    float v;
    if (c < 3) {
      v = centerb[(b * 3 + c) * Mm + m];
    } else if (c < 515) {
      const float* src = g3 + (size_t)(c - 3) * (Bb * Mm * SOMK) + b * (Mm * SOMK) + m * SOMK;
      v = src[0];
      for (int s = 1; s < SOMK; ++s) v = fmaxf(v, src[s]);
    } else {
      v = 0.f;
    }
    zhi[(size_t)p * 544 + c] = f2bf(v);
  }
}

__global__ __launch_bounds__(256) void final_max_kernel(
    const float* __restrict__ z2, float* __restrict__ out) {
  int gid = blockIdx.x * 256 + threadIdx.x;
  if (gid >= Bb * 1024) return;
  int b = gid / 1024, d = gid % 1024;
  const float* src = z2 + (size_t)d * (Bb * Mm) + b * Mm;
  float v = src[0];
  for (int m = 1; m < Mm; ++m) v = fmaxf(v, src[m]);
  out[gid] = v;
}

extern "C" void kernel_launch(void* const* d_in, const int* in_sizes, int n_in,
                              void* d_out, int out_size, void* d_ws, size_t ws_size,
                              hipStream_t stream) {
  (void)in_sizes; (void)n_in; (void)out_size;
  const float* x = (const float*)d_in[0];
  const float* sn = (const float*)d_in[1];
  const float* node = (const float*)d_in[2];
  const int* knnI = (const int*)d_in[3];
  const float* Wfp0 = (const float*)d_in[4];  const float* Pfp0 = (const float*)d_in[5];
  const float* Wfp1 = (const float*)d_in[6];  const float* Pfp1 = (const float*)d_in[7];
  const float* Wfp2 = (const float*)d_in[8];  const float* Pfp2 = (const float*)d_in[9];
  const float* Wfp3 = (const float*)d_in[10]; const float* Pfp3 = (const float*)d_in[11];
  const float* Wk0  = (const float*)d_in[12]; const float* Pk0  = (const float*)d_in[13];
  const float* Wk1  = (const float*)d_in[14]; const float* Pk1  = (const float*)d_in[15];
  const float* Wf0  = (const float*)d_in[16]; const float* Pf0  = (const float*)d_in[17];
  const float* Wf1  = (const float*)d_in[18]; const float* Pf1  = (const float*)d_in[19];
  float* out = (float*)d_out;

  char* ws = (char*)d_ws;
  size_t off = 0;
  auto alloc = [&](size_t bytes) -> void* {
    void* p = ws + off;
    off += (bytes + 255) & ~(size_t)255;
    return p;
  };
  float* counts    = (float*)alloc(512 * 4);
  float* cl_sum    = (float*)alloc(1536 * 4);
  float* som_node  = (float*)alloc(1536 * 4);
  float* centerb   = (float*)alloc(1536 * 4);
  int*   min_idx   = (int*)alloc((size_t)Bb * KN * 4);
  float* node_feat = (float*)alloc((size_t)Bb * Mm * 384 * 4);

  // pre-split weight buffers (hi/lo, padded cin)
  const int cinp_fp1 = 64, cinp_fp2 = 128, cinp_fp3 = 320;
  const int cinp_k0 = 416, cinp_k1 = 512, cinp_f0 = 544, cinp_f1 = 768;
  unsigned short *Wh[7], *Wl[7];
  int wtot[7] = {128 * 64, 256 * 128, 384 * 320, 512 * 416, 512 * 512, 768 * 544, 1024 * 768};
  for (int i = 0; i < 7; ++i) {
    Wh[i] = (unsigned short*)alloc((size_t)wtot[i] * 2);
    Wl[i] = (unsigned short*)alloc((size_t)wtot[i] * 2);
  }

  unsigned short* ghi  = (unsigned short*)alloc(4608ull * 416 * 2);
  unsigned short* g2hi = (unsigned short*)alloc(4608ull * 512 * 2);
  float* g3 = (float*)alloc(512ull * 4608 * 4);
  unsigned short* zbhi = (unsigned short*)alloc(512ull * 544 * 2);
  unsigned short* z1hi = (unsigned short*)alloc(512ull * 768 * 2);
  float* z2 = (float*)alloc(1024ull * 512 * 4);
  size_t small_end = off;

  // per-chunk: A1 (320ch bf16) 640 B/pt + y1 (128ch bf16) 256 B/pt = 896 B/pt
  size_t per_b = 896ull * KN;
  int Bc = 1;
  if (small_end + 8 * per_b + 4096 <= ws_size) Bc = 8;
  else if (small_end + 4 * per_b + 4096 <= ws_size) Bc = 4;
  else if (small_end + 2 * per_b + 4096 <= ws_size) Bc = 2;
  int Pc = Bc * KN;
  unsigned short* A1hi = (unsigned short*)alloc(320ull * Pc * 2);
  unsigned short* y1hi = (unsigned short*)alloc(128ull * Pc * 2);

  hipMemsetAsync(counts, 0, 512 * 4, stream);
  hipMemsetAsync(cl_sum, 0, 1536 * 4, stream);
  hipMemsetAsync(node_feat, 0, (size_t)Bb * Mm * 384 * 4, stream);
  som_assign_kernel<<<dim3(Nn / 256, Bb), 256, 0, stream>>>(x, node, min_idx, counts, cl_sum);
  som_node_kernel<<<6, 256, 0, stream>>>(cl_sum, counts, som_node);

  {
    WsplitArgs wa;
    const float* Wsrc[7] = {Wfp1, Wfp2, Wfp3, Wk0, Wk1, Wf0, Wf1};
    int cins[7] = {64, 128, 320, 387, 512, 515, 768};
    int cinps[7] = {cinp_fp1, cinp_fp2, cinp_fp3, cinp_k0, cinp_k1, cinp_f0, cinp_f1};
    for (int i = 0; i < 7; ++i)
      wa.d[i] = WsplitDesc{Wsrc[i], Wh[i], Wl[i], cins[i], cinps[i], wtot[i]};
    split_w_kernel<<<dim3(128, 7), 256, 0, stream>>>(wa);
  }

  for (int b0 = 0; b0 < Bb; b0 += Bc) {
    // fp0: fused decentering + f32 GEMM (cin=6) -> bf16 into A1 cols 0..63
    conv_gemm_t_kernel<<<dim3(Pc / 64, 1), 256, 0, stream>>>(
        x, sn, som_node, min_idx, b0, Wfp0, Pfp0, A1hi, 320, 0, 6, 64, Pc);
    // fp1: 64 -> 128
    mfma3_gemm_kernel<0><<<dim3(Pc / 128, 1), 256, 0, stream>>>(
        A1hi, 320, 0, 64, Wh[0], Wl[0], cinp_fp1, Pfp1, 128,
        nullptr, y1hi, 128, 0, Pc, nullptr, nullptr, 0);
    // fp2: 128 -> 256 into A1 cols 64..319
    mfma3_gemm_kernel<0><<<dim3(Pc / 128, 2), 256, 0, stream>>>(
        y1hi, 128, 0, 128, Wh[1], Wl[1], cinp_fp2, Pfp2, 256,
        nullptr, A1hi, 320, 64, Pc, nullptr, nullptr, 0);
    // fp3: 320 -> 384, fused segment-max (global atomicMax into node_feat)
    mfma3_gemm_kernel<2><<<dim3(Pc / 128, 3), 256, 0, stream>>>(
        A1hi, 320, 0, 320, Wh[2], Wl[2], cinp_fp3, Pfp3, 384,
        nullptr, nullptr, 0, 0, Pc, (unsigned*)node_feat, min_idx + b0 * KN, b0);
  }

  build_g_t_kernel<<<4608, 256, 0, stream>>>(som_node, node_feat, knnI, ghi, centerb);
  // knn0: 416 -> 512
  mfma3_gemm_kernel<0><<<dim3(36, 4), 256, 0, stream>>>(
      ghi, 416, 0, 416, Wh[3], Wl[3], cinp_k0, Pk0, 512,
      nullptr, g2hi, 512, 0, 4608, nullptr, nullptr, 0);
  // knn1: 512 -> 512, f32 out g3
  mfma3_gemm_kernel<1><<<dim3(36, 4), 256, 0, stream>>>(
      g2hi, 512, 0, 512, Wh[4], Wl[4], cinp_k1, Pk1, 512,
      g3, nullptr, 0, 0, 4608, nullptr, nullptr, 0);
  build_z_t_kernel<<<512, 256, 0, stream>>>(centerb, g3, zbhi);
  // fin0: 544 -> 768
  mfma3_gemm_kernel<0><<<dim3(4, 6), 256, 0, stream>>>(
      zbhi, 544, 0, 544, Wh[5], Wl[5], cinp_f0, Pf0, 768,
      nullptr, z1hi, 768, 0, 512, nullptr, nullptr, 0);
  // fin1: 768 -> 1024, f32 out z2
  mfma3_gemm_kernel<1><<<dim3(4, 8), 256, 0, stream>>>(
      z1hi, 768, 0, 768, Wh[6], Wl[6], cinp_f1, Pf1, 1024,
      z2, nullptr, 0, 0, 512, nullptr, nullptr, 0);
  final_max_kernel<<<32, 256, 0, stream>>>(z2, out);
}